// Round 12
// baseline (511.111 us; speedup 1.0000x reference)
//
#include <hip/hip_runtime.h>
#include <hip/hip_bf16.h>
#include <hip/hip_fp16.h>
#include <math.h>

#define Dm 256
#define Hh 4
#define Nn 4096
#define Mq 4096

typedef __attribute__((ext_vector_type(8))) short bf16x8;
typedef __attribute__((ext_vector_type(4))) float f32x4;
typedef _Float16 __attribute__((ext_vector_type(4))) f16x4;
typedef __fp16 __attribute__((ext_vector_type(2))) h16x2;

#define MFMA_BF16(a,b,c) __builtin_amdgcn_mfma_f32_16x16x32_bf16(a,b,c,0,0,0)
#define MFMA_F16x16(a,b,c) __builtin_amdgcn_mfma_f32_16x16x16f16(a,b,c,0,0,0)

#define MB (1u<<20)
// ---- workspace layout (bytes); <=31MB used ----
#define OFF_FLAG  0
#define OFF_SMIN  64                  // unsigned key
#define OFF_KMAX  128                 // 4 u32
#define OFF_MT    8192                // 16384 f32 (64KB)
#define OFF_DENP  (128u<<10)          // 16384*8 f32 (512KB)
#define OFF_WB    (3u*MB/2)           // 655360 bf16 (1.25MB)
#define OFF_BITS  (3u*MB)             // 2MB bitmask (dead after k_pvw)
#define OFF_ATTNT (3u*MB)             // bf16 [n][256] 2MB (alias bits)
#define OFF_QB    (5u*MB)             // bf16 [h][n][64] 2MB
#define OFF_KB    (7u*MB)             // bf16 [h][m][64] swizzled 2MB
#define OFF_VB    (9u*MB)             // fp16 [h][dd][m] 2MB
#define OFF_HCAT  (11u*MB)            // bf16 [n][512] 4MB
#define OFF_OPART (15u*MB)            // f16 [8][c][n] 16MB (alias xt/st region)
#define OFF_XT    (17u*MB)            // bf16 [n][256] 2MB (dead after k_qkv)
#define OFF_ST    (19u*MB)            // bf16 [n][256] 2MB (dead after k_qkv)
#define OFF_H1T   (15u*MB)            // bf16 [n][512] 4MB (alias opart, after k_finish)

#define WOFF_Q  0
#define WOFF_K  65536
#define WOFF_V  131072
#define WOFF_M  196608
#define WOFF_1  262144
#define WOFF_2  524288

__device__ __forceinline__ unsigned short f2bf(float x) {
    unsigned u = __float_as_uint(x);
    u += 0x7FFF + ((u >> 16) & 1);
    return (unsigned short)(u >> 16);
}
__device__ __forceinline__ float bf2f(unsigned short b) {
    return __uint_as_float(((unsigned)b) << 16);
}
__device__ __forceinline__ unsigned fkey(float f) {
    unsigned u = __float_as_uint(f);
    return (u & 0x80000000u) ? ~u : (u | 0x80000000u);
}
__device__ __forceinline__ float fdecode(unsigned k) {
    return (k & 0x80000000u) ? __uint_as_float(k ^ 0x80000000u) : __uint_as_float(~k);
}

// ---------------- transpose-cast + (block 0) mask dtype detect + inits ----------------
__global__ __launch_bounds__(256) void k_prep(const float* __restrict__ x,
                                              const float* __restrict__ source,
                                              unsigned short* __restrict__ xt,
                                              unsigned short* __restrict__ st,
                                              unsigned short* __restrict__ hcat,
                                              const unsigned char* __restrict__ maskb,
                                              int* __restrict__ flag,
                                              unsigned* __restrict__ kmax,
                                              unsigned* __restrict__ sminkey) {
    const int z = blockIdx.z;
    const float* src = z ? source : x;
    unsigned short* dst = z ? st : xt;
    unsigned short* dst2 = z ? nullptr : hcat;
    const int l = threadIdx.x & 63, g = threadIdx.x >> 6;
    const int c = blockIdx.y * 64 + l;
    const int n0 = blockIdx.x * 32 + g * 8;
    float4 v0 = *(const float4*)(src + (size_t)c * Nn + n0);
    float4 v1 = *(const float4*)(src + (size_t)c * Nn + n0 + 4);
    float vv[8] = {v0.x, v0.y, v0.z, v0.w, v1.x, v1.y, v1.z, v1.w};
    #pragma unroll
    for (int j = 0; j < 8; j++) {
        unsigned short b = f2bf(vv[j]);
        dst[(size_t)(n0 + j) * 256 + c] = b;
        if (dst2) dst2[(size_t)(n0 + j) * 512 + c] = b;
    }
    if (blockIdx.x == 0 && blockIdx.y == 0 && z == 0) {
        __shared__ int cnt[5];
        if (threadIdx.x < 5) cnt[threadIdx.x] = 0;
        if (threadIdx.x < 4) kmax[threadIdx.x] = 0u;
        if (threadIdx.x == 0) *sminkey = 0xFFFFFFFFu;
        __syncthreads();
        for (int i = threadIdx.x; i < 16384; i += 256) {
            unsigned char b = maskb[i];
            if (b) {
                atomicAdd(&cnt[i & 3], 1);
                if ((i & 7) == 4) atomicAdd(&cnt[4], 1);
            }
        }
        __syncthreads();
        if (threadIdx.x == 0) {
            int f;
            if (cnt[3] > 0 && cnt[0] == 0)        f = 3;
            else if (cnt[1] | cnt[2] | cnt[3])    f = 1;
            else if (cnt[4] > 0)                  f = 0;
            else                                  f = 2;
            *flag = f;
        }
    }
}

// ---------------- mask -> bitmask ----------------
__global__ void k_maskbits(const void* __restrict__ mp, const int* __restrict__ flagp,
                           unsigned char* __restrict__ bits) {
    size_t i = (size_t)blockIdx.x * 256 + threadIdx.x;
    const int flag = *flagp;
    size_t base = i * 8;
    unsigned b = 0;
    if (flag == 1) {
        unsigned long long u = *(const unsigned long long*)((const unsigned char*)mp + base);
        #pragma unroll
        for (int j = 0; j < 8; j++) b |= (unsigned)(((u >> (8*j)) & 0xFFull) != 0ull) << j;
    } else if (flag == 0) {
        const int* p = (const int*)mp;
        #pragma unroll
        for (int j = 0; j < 8; j++) b |= (unsigned)(p[base + j] != 0) << j;
    } else if (flag == 3) {
        const float* p = (const float*)mp;
        #pragma unroll
        for (int j = 0; j < 8; j++) b |= (unsigned)(p[base + j] != 0.0f) << j;
    } else {
        const unsigned long long* p = (const unsigned long long*)mp;
        #pragma unroll
        for (int j = 0; j < 8; j++) b |= (unsigned)(p[base + j] != 0ull) << j;
    }
    bits[i] = (unsigned char)b;
}

// ---------------- cast all weights to bf16 ----------------
__global__ void k_wcast(const float* __restrict__ Wq, const float* __restrict__ Wk,
                        const float* __restrict__ Wv, const float* __restrict__ Wm,
                        const float* __restrict__ W1, const float* __restrict__ W2,
                        unsigned short* __restrict__ wb) {
    size_t i = (size_t)blockIdx.x * 256 + threadIdx.x;
    const float* s; size_t off;
    if      (i < 65536)               { s = Wq; off = i; }
    else if (i < 131072)              { s = Wk; off = i - 65536; }
    else if (i < 196608)              { s = Wv; off = i - 131072; }
    else if (i < 262144)              { s = Wm; off = i - 196608; }
    else if (i < 524288)              { s = W1; off = i - 262144; }
    else                              { s = W2; off = i - 524288; }
    wb[i] = f2bf(s[off]);
}

// ---------------- MFMA GEMM body ----------------
template<int KK, int JT>
__device__ __forceinline__ void gemm_body(const unsigned short* __restrict__ wb,
                                          const float* __restrict__ bias,
                                          const unsigned short* __restrict__ xt,
                                          void* __restrict__ out, int mode,
                                          int bx, int by) {
    const int tid = threadIdx.x, w = tid >> 6, lane = tid & 63;
    const int lg = lane >> 4, lr = lane & 15;
    const int o_base = by * 64 + w * 16;
    const int n_base = bx * (16 * JT);
    f32x4 acc[JT];
    #pragma unroll
    for (int j = 0; j < JT; j++) acc[j] = (f32x4){0.f, 0.f, 0.f, 0.f};
    const unsigned short* wrow = wb + (size_t)(o_base + lr) * KK + lg * 8;
    const unsigned short* xrow = xt + (size_t)(n_base + lr) * KK + lg * 8;
    #pragma unroll
    for (int k0 = 0; k0 < KK; k0 += 32) {
        bf16x8 af = *(const bf16x8*)(wrow + k0);
        #pragma unroll
        for (int j = 0; j < JT; j++) {
            bf16x8 bfr = *(const bf16x8*)(xrow + (size_t)j * 16 * KK + k0);
            acc[j] = MFMA_BF16(af, bfr, acc[j]);
        }
    }
    float bv[4];
    #pragma unroll
    for (int r = 0; r < 4; r++) bv[r] = bias[o_base + lg * 4 + r];
    #pragma unroll
    for (int j = 0; j < JT; j++) {
        #pragma unroll
        for (int r = 0; r < 4; r++) {
            int o = o_base + lg * 4 + r;
            int n = n_base + j * 16 + lr;
            float v = acc[j][r] + bv[r];
            if (mode == 0) {
                ((float*)out)[(size_t)o * Nn + n] = v;
            } else if (mode == 1) {
                ((unsigned short*)out)[(((size_t)(o & 3)) * Nn + n) * 64 + (o >> 2)] = f2bf(v);
            } else if (mode == 2) {
                union { _Float16 h; unsigned short u; } cv; cv.h = (_Float16)v;
                ((unsigned short*)out)[(((size_t)(o & 3)) * 64 + (o >> 2)) * Mq + n] = cv.u;
            } else if (mode == 3) {
                ((unsigned short*)out)[(size_t)n * 512 + 256 + o] = f2bf(v);
            } else if (mode == 4) {
                ((unsigned short*)out)[(size_t)n * 512 + o] = f2bf(fmaxf(v, 0.f));
            } else {
                int dd = o >> 2, hh = o & 3, g = dd >> 3, pos = dd & 7;
                int slot = g ^ (n & 7);
                ((unsigned short*)out)[(((size_t)hh * Mq + n)) * 64 + slot * 8 + pos] = f2bf(v);
            }
        }
    }
}

template<int KK, int JT>
__global__ __launch_bounds__(256) void k_mgemm(const unsigned short* __restrict__ wb,
                                               const float* __restrict__ bias,
                                               const unsigned short* __restrict__ xt,
                                               void* __restrict__ out, int mode) {
    gemm_body<KK, JT>(wb, bias, xt, out, mode, blockIdx.x, blockIdx.y);
}

__global__ __launch_bounds__(256) void k_qkv(const unsigned short* __restrict__ wb,
                                             const float* __restrict__ bq,
                                             const float* __restrict__ bk,
                                             const float* __restrict__ bv,
                                             const unsigned short* __restrict__ xt,
                                             const unsigned short* __restrict__ st,
                                             void* __restrict__ qb, void* __restrict__ kb,
                                             void* __restrict__ vb) {
    const int z = blockIdx.z;
    const float* bias = (z == 0) ? bq : ((z == 1) ? bk : bv);
    const unsigned short* X = (z == 0) ? xt : st;
    void* out = (z == 0) ? qb : ((z == 1) ? kb : vb);
    int mode = (z == 0) ? 1 : ((z == 1) ? 5 : 2);
    gemm_body<256, 4>(wb + z * 65536, bias, X, out, mode, blockIdx.x, blockIdx.y);
}

// ---------------- norm-based row-max bound ----------------
__global__ __launch_bounds__(256) void k_knorm(const unsigned short* __restrict__ kb,
                                               unsigned* __restrict__ kmax) {
    const int h = blockIdx.y;
    const int m = blockIdx.x * 256 + threadIdx.x;
    const unsigned short* row = kb + ((size_t)(h * Mq + m) << 6);
    float s = 0.f;
    #pragma unroll
    for (int i = 0; i < 64; i++) { float v = bf2f(row[i]); s = fmaf(v, v, s); }
    __shared__ float red[256];
    red[threadIdx.x] = s;
    __syncthreads();
    for (int st = 128; st > 0; st >>= 1) {
        if (threadIdx.x < st) red[threadIdx.x] = fmaxf(red[threadIdx.x], red[threadIdx.x + st]);
        __syncthreads();
    }
    if (threadIdx.x == 0) atomicMax(kmax + h, __float_as_uint(red[0]));
}

__global__ __launch_bounds__(256) void k_qnorm(const unsigned short* __restrict__ qb,
                                               const unsigned* __restrict__ kmax,
                                               float* __restrict__ mtarr) {
    const int row = blockIdx.x * 256 + threadIdx.x;   // h*Nn + n
    const unsigned short* qr = qb + ((size_t)row << 6);
    float s = 0.f;
    #pragma unroll
    for (int i = 0; i < 64; i++) { float v = bf2f(qr[i]); s = fmaf(v, v, s); }
    float k2 = __uint_as_float(kmax[row >> 12]);
    mtarr[row] = sqrtf(s * k2) * 0.125f;   // |q|*|k|max/8 >= rowmax
}

// ---------------- global min of raw scores (round-7 512-thr shape + atomicMin) ----------------
// grid (32, 16), 512 threads; per wave n16 all heads; m256 per block, LDS-staged K.
__global__ __launch_bounds__(512) void k_min(
    const unsigned short* __restrict__ qb, const unsigned short* __restrict__ kb,
    unsigned* __restrict__ sminkey) {
    __shared__ unsigned short kbuf[2][8192];   // [buf][h][m32][64] 32KB
    const int tid = threadIdx.x;
    const int w = tid >> 6, lane = tid & 63;
    const int lg = lane >> 4, lr = lane & 15;
    const int n0 = blockIdx.x * 128 + w * 16;
    const int m0 = blockIdx.y * 256;

    bf16x8 qf[4][2];
    #pragma unroll
    for (int h = 0; h < 4; h++)
        #pragma unroll
        for (int kh = 0; kh < 2; kh++)
            qf[h][kh] = *(const bf16x8*)(qb + (((size_t)h * Nn + n0 + lr) << 6) + kh*32 + lg*8);

    const int h0 = tid >> 8, q0 = tid & 255;
    const unsigned short* src0 = kb + (((size_t)h0 * Mq + m0) << 6) + q0 * 8;
    const unsigned short* src1 = kb + (((size_t)(h0 + 2) * Mq + m0) << 6) + q0 * 8;
    unsigned short* dst0 = &kbuf[0][h0 * 2048 + q0 * 8];
    unsigned short* dst1 = &kbuf[0][(h0 + 2) * 2048 + q0 * 8];

    float mn = INFINITY;

    bf16x8 r0 = *(const bf16x8*)(src0);
    bf16x8 r1 = *(const bf16x8*)(src1);
    *(bf16x8*)dst0 = r0;
    *(bf16x8*)dst1 = r1;
    __syncthreads();
    r0 = *(const bf16x8*)(src0 + 2048);
    r1 = *(const bf16x8*)(src1 + 2048);

    for (int t = 0; t < 8; t++) {
        const unsigned short* kB = &kbuf[t & 1][0];
        #pragma unroll
        for (int mi = 0; mi < 2; mi++) {
            const int rowoff = (mi * 16 + lr) * 64;
            #pragma unroll
            for (int h = 0; h < 4; h++) {
                bf16x8 a0 = *(const bf16x8*)(kB + h*2048 + rowoff + ((lg ^ (lr & 7)) << 3));
                bf16x8 a1 = *(const bf16x8*)(kB + h*2048 + rowoff + (((lg + 4) ^ (lr & 7)) << 3));
                f32x4 acc = (f32x4){0.f, 0.f, 0.f, 0.f};
                acc = MFMA_BF16(a0, qf[h][0], acc);
                acc = MFMA_BF16(a1, qf[h][1], acc);
                mn = fminf(mn, fminf(fminf(acc[0], acc[1]), fminf(acc[2], acc[3])));
            }
        }
        if (t < 7) {
            *(bf16x8*)(dst0 + (((t + 1) & 1) ? 8192 : 0)) = r0;
            *(bf16x8*)(dst1 + (((t + 1) & 1) ? 8192 : 0)) = r1;
        }
        __syncthreads();
        if (t < 6) {
            r0 = *(const bf16x8*)(src0 + (size_t)(t + 2) * 2048);
            r1 = *(const bf16x8*)(src1 + (size_t)(t + 2) * 2048);
        }
    }

    for (int off = 1; off < 64; off <<= 1) mn = fminf(mn, __shfl_xor(mn, off));
    __shared__ float wmin[8];
    if (lane == 0) wmin[w] = mn;
    __syncthreads();
    if (tid == 0) {
        float m2 = wmin[0];
        #pragma unroll
        for (int i = 1; i < 8; i++) m2 = fminf(m2, wmin[i]);
        atomicMin(sminkey, fkey(m2 * 0.125f));
    }
}

// ---------------- fused flash PV + weights: grid (64 nb, 8 mb), 256 thr (4 waves x n16), all heads ----------------
__global__ __launch_bounds__(256) void k_pvw(
    const unsigned short* __restrict__ qb, const unsigned short* __restrict__ kb,
    const unsigned short* __restrict__ vbh,
    const unsigned long long* __restrict__ bits,
    const unsigned* __restrict__ skey, const float* __restrict__ mtarr,
    float* __restrict__ wout, float* __restrict__ denp, unsigned short* __restrict__ opart) {
    __shared__ unsigned short kbuf[2][4096];   // [buf][m64][64] bf16 16KB
    __shared__ unsigned short vbuf[2][4096];   // [buf][(mi4 ds4)16 lr][slot4][4] f16 16KB
    const int tid = threadIdx.x;
    const int w = tid >> 6, lane = tid & 63;
    const int lg = lane >> 4, lr = lane & 15;
    const int mb = blockIdx.y;
    const int n0 = blockIdx.x * 64 + w * 16;
    const int m0 = mb * 512;
    const float smin = fdecode(*skey);
    const float sminc = fmaxf(smin, 0.f);

    bf16x8 qf[4][2];
    float cT[4], cF[4];
    #pragma unroll
    for (int h = 0; h < 4; h++) {
        const size_t qrow = ((size_t)h * Nn + n0 + lr) << 6;
        qf[h][0] = *(const bf16x8*)(qb + qrow + lg*8);
        qf[h][1] = *(const bf16x8*)(qb + qrow + 32 + lg*8);
        float mtE = mtarr[(size_t)h * Nn + n0 + lr] + sminc;
        cT[h] = -mtE * 1.44269504f;
        cF[h] = cT[h] + smin * 1.44269504f;
    }

    f32x4 oacc[4][4];   // [h][ds]
    #pragma unroll
    for (int h = 0; h < 4; h++)
        #pragma unroll
        for (int ds = 0; ds < 4; ds++) oacc[h][ds] = (f32x4){0.f, 0.f, 0.f, 0.f};
    float dsum[4] = {0.f, 0.f, 0.f, 0.f};

    const int vj = tid & 7;
    const int vdd0 = tid >> 3, vdd1 = 32 + (tid >> 3);
    int vdstA, vdstB, vdstC, vdstD;
    {
        int vds = vdd0 >> 4, vlr = vdd0 & 15, vmi = vj >> 1;
        int vswz = (vlr >> 2) & 3;
        int vbase = ((vmi * 4 + vds) * 16 + vlr) * 4;
        vdstA = (vbase + (((vj & 1) * 2 + 0) ^ vswz)) * 4;
        vdstB = (vbase + (((vj & 1) * 2 + 1) ^ vswz)) * 4;
        vds = vdd1 >> 4; vlr = vdd1 & 15;
        vswz = (vlr >> 2) & 3;
        vbase = ((vmi * 4 + vds) * 16 + vlr) * 4;
        vdstC = (vbase + (((vj & 1) * 2 + 0) ^ vswz)) * 4;
        vdstD = (vbase + (((vj & 1) * 2 + 1) ^ vswz)) * 4;
    }

    union U8 { bf16x8 v; unsigned long long q[2]; };
    U8 rv0, rv1;
    // step s: t = s>>2, h = s&3; stage K_h/V_h for m-chunk t
    bf16x8 rk0 = *(const bf16x8*)(kb + (((size_t)0 * Mq + m0) << 6) + tid * 8);
    bf16x8 rk1 = *(const bf16x8*)(kb + (((size_t)0 * Mq + m0) << 6) + 2048 + tid * 8);
    rv0.v = *(const bf16x8*)(vbh + (size_t)(0 * 64 + vdd0) * Mq + m0 + vj * 8);
    rv1.v = *(const bf16x8*)(vbh + (size_t)(0 * 64 + vdd1) * Mq + m0 + vj * 8);
    *(bf16x8*)&kbuf[0][tid * 8] = rk0;
    *(bf16x8*)&kbuf[0][2048 + tid * 8] = rk1;
    *(unsigned long long*)&vbuf[0][vdstA] = rv0.q[0];
    *(unsigned long long*)&vbuf[0][vdstB] = rv0.q[1];
    *(unsigned long long*)&vbuf[0][vdstC] = rv1.q[0];
    *(unsigned long long*)&vbuf[0][vdstD] = rv1.q[1];
    __syncthreads();
    // load s=1 (t=0, h=1)
    rk0 = *(const bf16x8*)(kb + (((size_t)1 * Mq + m0) << 6) + tid * 8);
    rk1 = *(const bf16x8*)(kb + (((size_t)1 * Mq + m0) << 6) + 2048 + tid * 8);
    rv0.v = *(const bf16x8*)(vbh + (size_t)(1 * 64 + vdd0) * Mq + m0 + vj * 8);
    rv1.v = *(const bf16x8*)(vbh + (size_t)(1 * 64 + vdd1) * Mq + m0 + vj * 8);

    const unsigned long long* brow = bits + (((size_t)(n0 + lr)) << 6) + (m0 >> 6);
    const int kslot0 = (lg ^ (lr & 7)) << 3;
    const int kslot1 = ((lg + 4) ^ (lr & 7)) << 3;
    const int vrslot = (lg ^ ((lr >> 2) & 3)) * 4;

    unsigned long long bw = brow[0];
    unsigned long long bw_next = 0ull;
    f32x4 wsum[4];

    for (int s = 0; s < 32; s++) {
        const int t = s >> 2, h = s & 3;
        const unsigned short* kB = &kbuf[s & 1][0];
        const unsigned short* vB = &vbuf[s & 1][0];
        if (h == 0) {
            #pragma unroll
            for (int mi = 0; mi < 4; mi++) wsum[mi] = (f32x4){0.f, 0.f, 0.f, 0.f};
        }
        #pragma unroll
        for (int mi = 0; mi < 4; mi++) {
            const int rowoff = (mi * 16 + lr) * 64;
            bf16x8 a0 = *(const bf16x8*)(kB + rowoff + kslot0);
            bf16x8 a1 = *(const bf16x8*)(kB + rowoff + kslot1);
            f16x4 vf[4];
            #pragma unroll
            for (int ds = 0; ds < 4; ds++)
                vf[ds] = *(const f16x4*)&vB[((mi * 4 + ds) * 16 + lr) * 16 + vrslot];
            f32x4 acc = (f32x4){0.f, 0.f, 0.f, 0.f};
            acc = MFMA_BF16(a0, qf[h][0], acc);
            acc = MFMA_BF16(a1, qf[h][1], acc);
            wsum[mi] += acc;
            const int shb = mi * 16 + lg * 4;
            const unsigned nib = (unsigned)(bw >> shb) & 0xFu;
            float p0 = exp2f(fmaf(acc[0], 0.18033688f, (nib & 1u) ? cT[h] : cF[h]));
            float p1 = exp2f(fmaf(acc[1], 0.18033688f, (nib & 2u) ? cT[h] : cF[h]));
            float p2 = exp2f(fmaf(acc[2], 0.18033688f, (nib & 4u) ? cT[h] : cF[h]));
            float p3 = exp2f(fmaf(acc[3], 0.18033688f, (nib & 8u) ? cT[h] : cF[h]));
            dsum[h] += (p0 + p1) + (p2 + p3);
            union { h16x2 h2[2]; f16x4 f4; } pu;
            pu.h2[0] = __builtin_amdgcn_cvt_pkrtz(p0, p1);
            pu.h2[1] = __builtin_amdgcn_cvt_pkrtz(p2, p3);
            f16x4 pf = pu.f4;
            #pragma unroll
            for (int ds = 0; ds < 4; ds++)
                oacc[h][ds] = MFMA_F16x16(pf, vf[ds], oacc[h][ds]);
        }
        if (h == 2 && t < 7) bw_next = brow[t + 1];   // prefetch next t's mask word
        if (h == 3) {
            // final weights for this (n16 x m64) tile
            #pragma unroll
            for (int mi = 0; mi < 4; mi++) {
                const int shb = mi * 16 + lg * 4;
                const unsigned nib = (unsigned)(bw >> shb) & 0xFu;
                f32x4 wv;
                wv[0] = fmaf(wsum[mi][0], 0.03125f, (nib & 1u) ? 0.f : smin);
                wv[1] = fmaf(wsum[mi][1], 0.03125f, (nib & 2u) ? 0.f : smin);
                wv[2] = fmaf(wsum[mi][2], 0.03125f, (nib & 4u) ? 0.f : smin);
                wv[3] = fmaf(wsum[mi][3], 0.03125f, (nib & 8u) ? 0.f : smin);
                __builtin_nontemporal_store(wv,
                    (f32x4*)(wout + (size_t)(n0 + lr) * Mq + m0 + t * 64 + mi * 16 + lg * 4));
            }
            bw = bw_next;
        }
        if (s < 31) {
            *(bf16x8*)&kbuf[(s + 1) & 1][tid * 8] = rk0;
            *(bf16x8*)&kbuf[(s + 1) & 1][2048 + tid * 8] = rk1;
            *(unsigned long long*)&vbuf[(s + 1) & 1][vdstA] = rv0.q[0];
            *(unsigned long long*)&vbuf[(s + 1) & 1][vdstB] = rv0.q[1];
            *(unsigned long long*)&vbuf[(s + 1) & 1][vdstC] = rv1.q[0];
            *(unsigned long long*)&vbuf[(s + 1) & 1][vdstD] = rv1.q[1];
        }
        __syncthreads();
        if (s < 30) {
            const int s2 = s + 2, t2 = s2 >> 2, h2 = s2 & 3;
            const size_t koff = (((size_t)h2 * Mq + m0 + t2 * 64) << 6);
            rk0 = *(const bf16x8*)(kb + koff + tid * 8);
            rk1 = *(const bf16x8*)(kb + koff + 2048 + tid * 8);
            rv0.v = *(const bf16x8*)(vbh + (size_t)(h2 * 64 + vdd0) * Mq + m0 + t2 * 64 + vj * 8);
            rv1.v = *(const bf16x8*)(vbh + (size_t)(h2 * 64 + vdd1) * Mq + m0 + t2 * 64 + vj * 8);
        }
    }

    #pragma unroll
    for (int h = 0; h < 4; h++) {
        dsum[h] += __shfl_xor(dsum[h], 16);
        dsum[h] += __shfl_xor(dsum[h], 32);
    }
    if (lane < 16) {
        #pragma unroll
        for (int h = 0; h < 4; h++)
            denp[((size_t)h * Nn + n0 + lane) * 8 + mb] = dsum[h];
    }

    unsigned short* op = opart + (size_t)mb * (Dm * Nn);
    #pragma unroll
    for (int h = 0; h < 4; h++)
        #pragma unroll
        for (int ds = 0; ds < 4; ds++) {
            int c = (ds * 16 + lr) * 4 + h;
            int n = n0 + lg * 4;
            union { h16x2 h2[2]; unsigned long long q; } pu;
            pu.h2[0] = __builtin_amdgcn_cvt_pkrtz(oacc[h][ds][0], oacc[h][ds][1]);
            pu.h2[1] = __builtin_amdgcn_cvt_pkrtz(oacc[h][ds][2], oacc[h][ds][3]);
            *(unsigned long long*)&op[(size_t)c * Nn + n] = pu.q;
        }
}

// ---------------- finish: sum 8 f16 partials, normalize, transpose -> attnT[n][c] bf16 ----------------
__global__ __launch_bounds__(256) void k_finish(const unsigned short* __restrict__ opart,
                                                const float* __restrict__ denp,
                                                unsigned short* __restrict__ attnT) {
    __shared__ float t[64][65];
    const int cb = blockIdx.y * 64, nb = blockIdx.x * 64;
    const int tid = threadIdx.x;
    #pragma unroll
    for (int e = 0; e < 16; e++) {
        int idx = e * 256 + tid;
        int c_l = idx >> 6, n_l = idx & 63;
        int c = cb + c_l, n = nb + n_l;
        float s = 0.f;
        #pragma unroll
        for (int y = 0; y < 8; y++) {
            union { unsigned short u; _Float16 h; } cv;
            cv.u = opart[(size_t)y * (Dm*Nn) + (size_t)c * Nn + n];
            s += (float)cv.h;
        }
        size_t row = (size_t)(c & 3) * Nn + n;
        float d = 0.f;
        #pragma unroll
        for (int mb = 0; mb < 8; mb++) d += denp[row*8 + mb];
        t[c_l][n_l] = s / d;
    }
    __syncthreads();
    #pragma unroll
    for (int e = 0; e < 16; e++) {
        int idx = e * 256 + tid;
        int n_l = idx >> 6, c_l = idx & 63;
        attnT[(size_t)(nb + n_l) * 256 + cb + c_l] = f2bf(t[c_l][n_l]);
    }
}

extern "C" void kernel_launch(void* const* d_in, const int* in_sizes, int n_in,
                              void* d_out, int out_size, void* d_ws, size_t ws_size,
                              hipStream_t stream) {
    const float* x      = (const float*)d_in[0];
    const float* source = (const float*)d_in[1];
    const void*  mask   = d_in[3];
    const float* Wq = (const float*)d_in[4];  const float* bq = (const float*)d_in[5];
    const float* Wk = (const float*)d_in[6];  const float* bk = (const float*)d_in[7];
    const float* Wv = (const float*)d_in[8];  const float* bv = (const float*)d_in[9];
    const float* Wm = (const float*)d_in[10]; const float* bm = (const float*)d_in[11];
    const float* W1 = (const float*)d_in[12]; const float* b1 = (const float*)d_in[13];
    const float* W2 = (const float*)d_in[14]; const float* b2 = (const float*)d_in[15];

    float* y    = (float*)d_out;                // [256,4096]
    float* wout = y + (size_t)Dm * Nn;          // [4096,4096]

    char* ws = (char*)d_ws;
    int*      flag  = (int*)(ws + OFF_FLAG);
    unsigned* skey  = (unsigned*)(ws + OFF_SMIN);
    unsigned* kmax  = (unsigned*)(ws + OFF_KMAX);
    float*    mtarr = (float*)(ws + OFF_MT);
    float*    denp  = (float*)(ws + OFF_DENP);
    unsigned short* wb    = (unsigned short*)(ws + OFF_WB);
    unsigned char*  bits  = (unsigned char*)(ws + OFF_BITS);
    unsigned short* qb    = (unsigned short*)(ws + OFF_QB);
    unsigned short* kb    = (unsigned short*)(ws + OFF_KB);
    unsigned short* vb    = (unsigned short*)(ws + OFF_VB);
    unsigned short* hcat  = (unsigned short*)(ws + OFF_HCAT);
    unsigned short* attnT = (unsigned short*)(ws + OFF_ATTNT);
    unsigned short* xt    = (unsigned short*)(ws + OFF_XT);
    unsigned short* st    = (unsigned short*)(ws + OFF_ST);
    unsigned short* opart = (unsigned short*)(ws + OFF_OPART);
    unsigned short* h1t   = (unsigned short*)(ws + OFF_H1T);

    k_prep<<<dim3(128, 4, 2), 256, 0, stream>>>(x, source, xt, st, hcat,
                                                (const unsigned char*)mask, flag, kmax, skey);
    k_maskbits<<<8192, 256, 0, stream>>>(mask, flag, bits);
    k_wcast<<<2560, 256, 0, stream>>>(Wq, Wk, Wv, Wm, W1, W2, wb);

    k_qkv<<<dim3(64, 4, 3), 256, 0, stream>>>(wb, bq, bk, bv, xt, st, qb, kb, vb);

    k_knorm<<<dim3(16, 4), 256, 0, stream>>>(kb, kmax);
    k_qnorm<<<64, 256, 0, stream>>>(qb, kmax, mtarr);

    k_min<<<dim3(32, 16), 512, 0, stream>>>(qb, kb, skey);

    k_pvw<<<dim3(64, 8), 256, 0, stream>>>(qb, kb, vb, (const unsigned long long*)bits,
                                           skey, mtarr, wout, denp, opart);
    k_finish<<<dim3(64, 4), 256, 0, stream>>>(opart, denp, attnT);

    k_mgemm<256, 4><<<dim3(64, 4), 256, 0, stream>>>(wb + WOFF_M, bm, attnT, hcat, 3);
    k_mgemm<512, 4><<<dim3(64, 8), 256, 0, stream>>>(wb + WOFF_1, b1, hcat, h1t, 4);
    k_mgemm<512, 4><<<dim3(64, 4), 256, 0, stream>>>(wb + WOFF_2, b2, h1t, y, 0);
}

// Round 13
// 215.247 us; speedup vs baseline: 2.3745x; 2.3745x over previous
//
#include <hip/hip_runtime.h>
#include <hip/hip_bf16.h>
#include <math.h>

#define Dm 256
#define Hh 4
#define Nn 4096
#define Mq 4096

typedef __attribute__((ext_vector_type(8))) short bf16x8;
typedef __attribute__((ext_vector_type(4))) float f32x4;
typedef _Float16 __attribute__((ext_vector_type(4))) f16x4;
typedef __fp16 __attribute__((ext_vector_type(2))) h16x2;

#define MFMA_BF16(a,b,c) __builtin_amdgcn_mfma_f32_16x16x32_bf16(a,b,c,0,0,0)
#define MFMA_F16x16(a,b,c) __builtin_amdgcn_mfma_f32_16x16x16f16(a,b,c,0,0,0)

#define MB (1u<<20)
// ---- workspace layout (bytes); r7 layout + skey ----
#define OFF_FLAG  0
#define OFF_SMIN  64                  // unsigned key
#define OFF_KMAX  128                 // 4 u32
#define OFF_MT    4096                // 16384 f32 (64KB)
#define OFF_DENP  (128u<<10)          // 16384*4 f32 (256KB)
#define OFF_WB    (3u*MB/2)           // 655360 bf16 (1.25MB)
#define OFF_BITS  (3u*MB)             // 2MB bitmask
#define OFF_QB    (5u*MB)             // bf16 [h][n][64] 2MB
#define OFF_KB    (7u*MB)             // bf16 [h][m][64] swizzled 2MB
#define OFF_VB    (9u*MB)             // fp16 [h][dd][m] 2MB
#define OFF_HCAT  (11u*MB)            // bf16 [n][512] 4MB
#define OFF_ATTNT (15u*MB)            // bf16 [n][256] 2MB
// overlap region (xt/st die after k_qkv; opart dies before h1t written)
#define OFF_XT    (17u*MB)            // bf16 [n][256] 2MB
#define OFF_ST    (19u*MB)            // bf16 [n][256] 2MB
#define OFF_OPART (17u*MB)            // bf16 [4][c][n] 8MB -> ends 25MB
#define OFF_H1T   (17u*MB)            // bf16 [n][512] 4MB

#define WOFF_Q  0
#define WOFF_K  65536
#define WOFF_V  131072
#define WOFF_M  196608
#define WOFF_1  262144
#define WOFF_2  524288

__device__ __forceinline__ unsigned short f2bf(float x) {
    unsigned u = __float_as_uint(x);
    u += 0x7FFF + ((u >> 16) & 1);
    return (unsigned short)(u >> 16);
}
__device__ __forceinline__ float bf2f(unsigned short b) {
    return __uint_as_float(((unsigned)b) << 16);
}
__device__ __forceinline__ unsigned fkey(float f) {
    unsigned u = __float_as_uint(f);
    return (u & 0x80000000u) ? ~u : (u | 0x80000000u);
}
__device__ __forceinline__ float fdecode(unsigned k) {
    return (k & 0x80000000u) ? __uint_as_float(k ^ 0x80000000u) : __uint_as_float(~k);
}

// ---------------- transpose-cast + (block 0) mask dtype detect + inits ----------------
__global__ __launch_bounds__(256) void k_prep(const float* __restrict__ x,
                                              const float* __restrict__ source,
                                              unsigned short* __restrict__ xt,
                                              unsigned short* __restrict__ st,
                                              unsigned short* __restrict__ hcat,
                                              const unsigned char* __restrict__ maskb,
                                              int* __restrict__ flag,
                                              unsigned* __restrict__ kmax,
                                              unsigned* __restrict__ sminkey) {
    const int z = blockIdx.z;
    const float* src = z ? source : x;
    unsigned short* dst = z ? st : xt;
    unsigned short* dst2 = z ? nullptr : hcat;
    const int l = threadIdx.x & 63, g = threadIdx.x >> 6;
    const int c = blockIdx.y * 64 + l;
    const int n0 = blockIdx.x * 32 + g * 8;
    float4 v0 = *(const float4*)(src + (size_t)c * Nn + n0);
    float4 v1 = *(const float4*)(src + (size_t)c * Nn + n0 + 4);
    float vv[8] = {v0.x, v0.y, v0.z, v0.w, v1.x, v1.y, v1.z, v1.w};
    #pragma unroll
    for (int j = 0; j < 8; j++) {
        unsigned short b = f2bf(vv[j]);
        dst[(size_t)(n0 + j) * 256 + c] = b;
        if (dst2) dst2[(size_t)(n0 + j) * 512 + c] = b;
    }
    if (blockIdx.x == 0 && blockIdx.y == 0 && z == 0) {
        __shared__ int cnt[5];
        if (threadIdx.x < 5) cnt[threadIdx.x] = 0;
        if (threadIdx.x < 4) kmax[threadIdx.x] = 0u;
        if (threadIdx.x == 0) *sminkey = 0xFFFFFFFFu;
        __syncthreads();
        for (int i = threadIdx.x; i < 16384; i += 256) {
            unsigned char b = maskb[i];
            if (b) {
                atomicAdd(&cnt[i & 3], 1);
                if ((i & 7) == 4) atomicAdd(&cnt[4], 1);
            }
        }
        __syncthreads();
        if (threadIdx.x == 0) {
            int f;
            if (cnt[3] > 0 && cnt[0] == 0)        f = 3;  // f32
            else if (cnt[1] | cnt[2] | cnt[3])    f = 1;  // u8/bool
            else if (cnt[4] > 0)                  f = 0;  // i32
            else                                  f = 2;  // i64
            *flag = f;
        }
    }
}

// ---------------- mask -> bitmask ----------------
__global__ void k_maskbits(const void* __restrict__ mp, const int* __restrict__ flagp,
                           unsigned char* __restrict__ bits) {
    size_t i = (size_t)blockIdx.x * 256 + threadIdx.x;
    const int flag = *flagp;
    size_t base = i * 8;
    unsigned b = 0;
    if (flag == 1) {
        unsigned long long u = *(const unsigned long long*)((const unsigned char*)mp + base);
        #pragma unroll
        for (int j = 0; j < 8; j++) b |= (unsigned)(((u >> (8*j)) & 0xFFull) != 0ull) << j;
    } else if (flag == 0) {
        const int* p = (const int*)mp;
        #pragma unroll
        for (int j = 0; j < 8; j++) b |= (unsigned)(p[base + j] != 0) << j;
    } else if (flag == 3) {
        const float* p = (const float*)mp;
        #pragma unroll
        for (int j = 0; j < 8; j++) b |= (unsigned)(p[base + j] != 0.0f) << j;
    } else {
        const unsigned long long* p = (const unsigned long long*)mp;
        #pragma unroll
        for (int j = 0; j < 8; j++) b |= (unsigned)(p[base + j] != 0ull) << j;
    }
    bits[i] = (unsigned char)b;
}

// ---------------- cast all weights to bf16 ----------------
__global__ void k_wcast(const float* __restrict__ Wq, const float* __restrict__ Wk,
                        const float* __restrict__ Wv, const float* __restrict__ Wm,
                        const float* __restrict__ W1, const float* __restrict__ W2,
                        unsigned short* __restrict__ wb) {
    size_t i = (size_t)blockIdx.x * 256 + threadIdx.x;
    const float* s; size_t off;
    if      (i < 65536)               { s = Wq; off = i; }
    else if (i < 131072)              { s = Wk; off = i - 65536; }
    else if (i < 196608)              { s = Wv; off = i - 131072; }
    else if (i < 262144)              { s = Wm; off = i - 196608; }
    else if (i < 524288)              { s = W1; off = i - 262144; }
    else                              { s = W2; off = i - 524288; }
    wb[i] = f2bf(s[off]);
}

// ---------------- MFMA GEMM body (r7) ----------------
template<int KK>
__device__ __forceinline__ void gemm_body(const unsigned short* __restrict__ wb,
                                          const float* __restrict__ bias,
                                          const unsigned short* __restrict__ xt,
                                          void* __restrict__ out, int mode,
                                          int bx, int by) {
    const int tid = threadIdx.x, w = tid >> 6, lane = tid & 63;
    const int lg = lane >> 4, lr = lane & 15;
    const int o_base = by * 64 + w * 16;
    const int n_base = bx * 64;
    f32x4 acc[4];
    #pragma unroll
    for (int j = 0; j < 4; j++) acc[j] = (f32x4){0.f, 0.f, 0.f, 0.f};
    const unsigned short* wrow = wb + (size_t)(o_base + lr) * KK + lg * 8;
    const unsigned short* xrow = xt + (size_t)(n_base + lr) * KK + lg * 8;
    #pragma unroll
    for (int k0 = 0; k0 < KK; k0 += 32) {
        bf16x8 af = *(const bf16x8*)(wrow + k0);
        #pragma unroll
        for (int j = 0; j < 4; j++) {
            bf16x8 bfr = *(const bf16x8*)(xrow + (size_t)j * 16 * KK + k0);
            acc[j] = MFMA_BF16(af, bfr, acc[j]);
        }
    }
    float bv[4];
    #pragma unroll
    for (int r = 0; r < 4; r++) bv[r] = bias[o_base + lg * 4 + r];
    #pragma unroll
    for (int j = 0; j < 4; j++) {
        #pragma unroll
        for (int r = 0; r < 4; r++) {
            int o = o_base + lg * 4 + r;
            int n = n_base + j * 16 + lr;
            float v = acc[j][r] + bv[r];
            if (mode == 0) {
                ((float*)out)[(size_t)o * Nn + n] = v;
            } else if (mode == 1) {
                ((unsigned short*)out)[(((size_t)(o & 3)) * Nn + n) * 64 + (o >> 2)] = f2bf(v);
            } else if (mode == 2) {
                union { _Float16 h; unsigned short u; } cv; cv.h = (_Float16)v;
                ((unsigned short*)out)[(((size_t)(o & 3)) * 64 + (o >> 2)) * Mq + n] = cv.u;
            } else if (mode == 3) {
                ((unsigned short*)out)[(size_t)n * 512 + 256 + o] = f2bf(v);
            } else if (mode == 4) {
                ((unsigned short*)out)[(size_t)n * 512 + o] = f2bf(fmaxf(v, 0.f));
            } else {
                int dd = o >> 2, hh = o & 3, g = dd >> 3, pos = dd & 7;
                int slot = g ^ (n & 7);
                ((unsigned short*)out)[(((size_t)hh * Mq + n)) * 64 + slot * 8 + pos] = f2bf(v);
            }
        }
    }
}

template<int KK>
__global__ __launch_bounds__(256) void k_mgemm(const unsigned short* __restrict__ wb,
                                               const float* __restrict__ bias,
                                               const unsigned short* __restrict__ xt,
                                               void* __restrict__ out, int mode) {
    gemm_body<KK>(wb, bias, xt, out, mode, blockIdx.x, blockIdx.y);
}

__global__ __launch_bounds__(256) void k_qkv(const unsigned short* __restrict__ wb,
                                             const float* __restrict__ bq,
                                             const float* __restrict__ bk,
                                             const float* __restrict__ bv,
                                             const unsigned short* __restrict__ xt,
                                             const unsigned short* __restrict__ st,
                                             void* __restrict__ qb, void* __restrict__ kb,
                                             void* __restrict__ vb) {
    const int z = blockIdx.z;
    const float* bias = (z == 0) ? bq : ((z == 1) ? bk : bv);
    const unsigned short* X = (z == 0) ? xt : st;
    void* out = (z == 0) ? qb : ((z == 1) ? kb : vb);
    int mode = (z == 0) ? 1 : ((z == 1) ? 5 : 2);
    gemm_body<256>(wb + z * 65536, bias, X, out, mode, blockIdx.x, blockIdx.y);
}

// ---------------- norm-based row-max bound ----------------
__global__ __launch_bounds__(256) void k_knorm(const unsigned short* __restrict__ kb,
                                               unsigned* __restrict__ kmax) {
    const int h = blockIdx.y;
    const int m = blockIdx.x * 256 + threadIdx.x;
    const unsigned short* row = kb + ((size_t)(h * Mq + m) << 6);
    float s = 0.f;
    #pragma unroll
    for (int i = 0; i < 64; i++) { float v = bf2f(row[i]); s = fmaf(v, v, s); }
    __shared__ float red[256];
    red[threadIdx.x] = s;
    __syncthreads();
    for (int st = 128; st > 0; st >>= 1) {
        if (threadIdx.x < st) red[threadIdx.x] = fmaxf(red[threadIdx.x], red[threadIdx.x + st]);
        __syncthreads();
    }
    if (threadIdx.x == 0) atomicMax(kmax + h, __float_as_uint(red[0]));
}

__global__ __launch_bounds__(256) void k_qnorm(const unsigned short* __restrict__ qb,
                                               const unsigned* __restrict__ kmax,
                                               float* __restrict__ mtarr) {
    const int row = blockIdx.x * 256 + threadIdx.x;   // h*Nn + n
    const unsigned short* qr = qb + ((size_t)row << 6);
    float s = 0.f;
    #pragma unroll
    for (int i = 0; i < 64; i++) { float v = bf2f(qr[i]); s = fmaf(v, v, s); }
    float k2 = __uint_as_float(kmax[row >> 12]);
    mtarr[row] = sqrtf(s * k2) * 0.125f;   // |q|*|k|max/8 >= rowmax
}

// ---------------- fused: unmasked weights + global min (r7 k_wout shape) ----------------
// grid (32, 16), 512 threads; per wave n16 all heads; m256 per block, LDS-staged K.
__global__ __launch_bounds__(512) void k_minwout(
    const unsigned short* __restrict__ qb, const unsigned short* __restrict__ kb,
    unsigned* __restrict__ sminkey, float* __restrict__ wout) {
    __shared__ unsigned short kbuf[2][8192];
    const int tid = threadIdx.x;
    const int w = tid >> 6, lane = tid & 63;
    const int lg = lane >> 4, lr = lane & 15;
    const int n0 = blockIdx.x * 128 + w * 16;
    const int m0 = blockIdx.y * 256;

    bf16x8 qf[4][2];
    #pragma unroll
    for (int h = 0; h < 4; h++)
        #pragma unroll
        for (int kh = 0; kh < 2; kh++)
            qf[h][kh] = *(const bf16x8*)(qb + (((size_t)h * Nn + n0 + lr) << 6) + kh*32 + lg*8);

    const int h0 = tid >> 8, q0 = tid & 255;
    const unsigned short* src0 = kb + (((size_t)h0 * Mq + m0) << 6) + q0 * 8;
    const unsigned short* src1 = kb + (((size_t)(h0 + 2) * Mq + m0) << 6) + q0 * 8;
    unsigned short* dst0 = &kbuf[0][h0 * 2048 + q0 * 8];
    unsigned short* dst1 = &kbuf[0][(h0 + 2) * 2048 + q0 * 8];

    float mn = INFINITY;

    bf16x8 r0 = *(const bf16x8*)(src0);
    bf16x8 r1 = *(const bf16x8*)(src1);
    *(bf16x8*)dst0 = r0;
    *(bf16x8*)dst1 = r1;
    __syncthreads();
    r0 = *(const bf16x8*)(src0 + 2048);
    r1 = *(const bf16x8*)(src1 + 2048);

    for (int t = 0; t < 8; t++) {
        const unsigned short* kB = &kbuf[t & 1][0];
        const int mch = m0 + t * 32;
        #pragma unroll
        for (int mi = 0; mi < 2; mi++) {
            const int rowoff = (mi * 16 + lr) * 64;
            f32x4 wsum = (f32x4){0.f, 0.f, 0.f, 0.f};
            #pragma unroll
            for (int h = 0; h < 4; h++) {
                bf16x8 a0 = *(const bf16x8*)(kB + h*2048 + rowoff + ((lg ^ (lr & 7)) << 3));
                bf16x8 a1 = *(const bf16x8*)(kB + h*2048 + rowoff + (((lg + 4) ^ (lr & 7)) << 3));
                f32x4 acc = (f32x4){0.f, 0.f, 0.f, 0.f};
                acc = MFMA_BF16(a0, qf[h][0], acc);
                acc = MFMA_BF16(a1, qf[h][1], acc);
                mn = fminf(mn, fminf(fminf(acc[0], acc[1]), fminf(acc[2], acc[3])));
                wsum += acc;
            }
            f32x4 wv;
            #pragma unroll
            for (int rr = 0; rr < 4; rr++) wv[rr] = wsum[rr] * 0.03125f;
            __builtin_nontemporal_store(wv,
                (f32x4*)(wout + (size_t)(n0 + lr) * Mq + mch + mi * 16 + lg * 4));
        }
        if (t < 7) {
            *(bf16x8*)(dst0 + (((t + 1) & 1) ? 8192 : 0)) = r0;
            *(bf16x8*)(dst1 + (((t + 1) & 1) ? 8192 : 0)) = r1;
        }
        __syncthreads();
        if (t < 6) {
            r0 = *(const bf16x8*)(src0 + (size_t)(t + 2) * 2048);
            r1 = *(const bf16x8*)(src1 + (size_t)(t + 2) * 2048);
        }
    }

    for (int off = 1; off < 64; off <<= 1) mn = fminf(mn, __shfl_xor(mn, off));
    __shared__ float wmin[8];
    if (lane == 0) wmin[w] = mn;
    __syncthreads();
    if (tid == 0) {
        float m2 = wmin[0];
        #pragma unroll
        for (int i = 1; i < 8; i++) m2 = fminf(m2, wmin[i]);
        atomicMin(sminkey, fkey(m2 * 0.125f));
    }
}

// ---------------- wfix: wout += smin * (1 - mask), elementwise ----------------
__global__ __launch_bounds__(256) void k_wfix(float* __restrict__ wout,
                                              const unsigned long long* __restrict__ bits,
                                              const unsigned* __restrict__ skey) {
    const float smin = fdecode(*skey);
    size_t base = ((size_t)blockIdx.x * 256 + threadIdx.x) * 16;
    unsigned nib = (unsigned)((bits[base >> 6] >> (base & 63)) & 0xFFFFull);
    float* p = wout + base;
    f32x4 v[4];
    #pragma unroll
    for (int q = 0; q < 4; q++) v[q] = ((const f32x4*)p)[q];
    #pragma unroll
    for (int j = 0; j < 16; j++)
        if (!((nib >> j) & 1u)) v[j >> 2][j & 3] += smin;
    #pragma unroll
    for (int q = 0; q < 4; q++) __builtin_nontemporal_store(v[q], (f32x4*)p + q);
}

// ---------------- flash PV (r7): grid (32, 16=h4*mb4), 512 thr, 8 waves x n16, full dd ----------------
__global__ __launch_bounds__(512) void k_pv(
    const unsigned short* __restrict__ qb, const unsigned short* __restrict__ kb,
    const unsigned short* __restrict__ vbh,
    const unsigned long long* __restrict__ bits,
    const unsigned* __restrict__ skey, const float* __restrict__ mtarr,
    float* __restrict__ denp, unsigned short* __restrict__ opart) {
    __shared__ unsigned short kbuf[2][4096];   // [buf][m64][64] bf16 16KB
    __shared__ unsigned short vbuf[2][4096];   // [buf][(mi4 ds4)16 lr][slot4][4] f16 16KB
    const int tid = threadIdx.x;
    const int w = tid >> 6, lane = tid & 63;
    const int lg = lane >> 4, lr = lane & 15;
    const int h = blockIdx.y & 3, mb = blockIdx.y >> 2;
    const int n0 = blockIdx.x * 128 + w * 16;
    const int m0 = mb * 1024;
    const float smin = fdecode(*skey);
    const float sminc = fmaxf(smin, 0.f);

    bf16x8 qf0 = *(const bf16x8*)(qb + (((size_t)h * Nn + n0 + lr) << 6) + lg*8);
    bf16x8 qf1 = *(const bf16x8*)(qb + (((size_t)h * Nn + n0 + lr) << 6) + 32 + lg*8);
    float mtE = mtarr[(size_t)h * Nn + n0 + lr] + sminc;
    const float cT = -mtE * 1.44269504f;
    const float cF = cT + smin * 1.44269504f;

    f32x4 oacc[4];
    #pragma unroll
    for (int ds = 0; ds < 4; ds++) oacc[ds] = (f32x4){0.f, 0.f, 0.f, 0.f};
    float dsum = 0.f;

    const unsigned short* ksrc = kb + (((size_t)h * Mq + m0) << 6) + tid * 8;
    const int vdd = tid >> 3, vj = tid & 7;
    const unsigned short* vsrc = vbh + (size_t)(h * 64 + vdd) * Mq + m0 + vj * 8;
    const int vds = vdd >> 4, vlr = vdd & 15, vmi = vj >> 1;
    const int vswz = (vlr >> 2) & 3;
    const int vbase = ((vmi * 4 + vds) * 16 + vlr) * 4;
    const int vdst0 = (vbase + (((vj & 1) * 2 + 0) ^ vswz)) * 4;
    const int vdst1 = (vbase + (((vj & 1) * 2 + 1) ^ vswz)) * 4;

    union { bf16x8 v; unsigned long long q[2]; } rv;
    bf16x8 rk = *(const bf16x8*)(ksrc);
    rv.v = *(const bf16x8*)(vsrc);
    *(bf16x8*)&kbuf[0][tid * 8] = rk;
    *(unsigned long long*)&vbuf[0][vdst0] = rv.q[0];
    *(unsigned long long*)&vbuf[0][vdst1] = rv.q[1];
    __syncthreads();
    rk = *(const bf16x8*)(ksrc + 4096);
    rv.v = *(const bf16x8*)(vsrc + 64);

    const unsigned long long* brow = bits + (((size_t)(n0 + lr)) << 6) + (m0 >> 6);
    const int kslot0 = (lg ^ (lr & 7)) << 3;
    const int kslot1 = ((lg + 4) ^ (lr & 7)) << 3;
    const int vrslot = (lg ^ ((lr >> 2) & 3)) * 4;

    for (int t = 0; t < 16; t++) {
        const unsigned short* kB = &kbuf[t & 1][0];
        const unsigned short* vB = &vbuf[t & 1][0];
        unsigned long long bw = brow[t];
        #pragma unroll
        for (int mi = 0; mi < 4; mi++) {
            const int rowoff = (mi * 16 + lr) * 64;
            bf16x8 a0 = *(const bf16x8*)(kB + rowoff + kslot0);
            bf16x8 a1 = *(const bf16x8*)(kB + rowoff + kslot1);
            f16x4 vf[4];
            #pragma unroll
            for (int ds = 0; ds < 4; ds++)
                vf[ds] = *(const f16x4*)&vB[((mi * 4 + ds) * 16 + lr) * 16 + vrslot];
            f32x4 acc = (f32x4){0.f, 0.f, 0.f, 0.f};
            acc = MFMA_BF16(a0, qf0, acc);
            acc = MFMA_BF16(a1, qf1, acc);
            const int shb = mi * 16 + lg * 4;
            float p0 = exp2f(fmaf(acc[0], 0.18033688f, ((bw >> (shb + 0)) & 1ull) ? cT : cF));
            float p1 = exp2f(fmaf(acc[1], 0.18033688f, ((bw >> (shb + 1)) & 1ull) ? cT : cF));
            float p2 = exp2f(fmaf(acc[2], 0.18033688f, ((bw >> (shb + 2)) & 1ull) ? cT : cF));
            float p3 = exp2f(fmaf(acc[3], 0.18033688f, ((bw >> (shb + 3)) & 1ull) ? cT : cF));
            dsum += (p0 + p1) + (p2 + p3);
            union { h16x2 h2[2]; f16x4 f4; } pu;
            pu.h2[0] = __builtin_amdgcn_cvt_pkrtz(p0, p1);
            pu.h2[1] = __builtin_amdgcn_cvt_pkrtz(p2, p3);
            f16x4 pf = pu.f4;
            #pragma unroll
            for (int ds = 0; ds < 4; ds++)
                oacc[ds] = MFMA_F16x16(pf, vf[ds], oacc[ds]);
        }
        if (t < 15) {
            *(bf16x8*)&kbuf[(t + 1) & 1][tid * 8] = rk;
            *(unsigned long long*)&vbuf[(t + 1) & 1][vdst0] = rv.q[0];
            *(unsigned long long*)&vbuf[(t + 1) & 1][vdst1] = rv.q[1];
        }
        __syncthreads();
        if (t < 14) {
            rk = *(const bf16x8*)(ksrc + (size_t)(t + 2) * 4096);
            rv.v = *(const bf16x8*)(vsrc + (size_t)(t + 2) * 64);
        }
    }

    dsum += __shfl_xor(dsum, 16);
    dsum += __shfl_xor(dsum, 32);
    if (lane < 16)
        denp[((size_t)h * Nn + n0 + lane) * 4 + mb] = dsum;

    unsigned short* op = opart + (size_t)mb * (Dm * Nn);
    #pragma unroll
    for (int ds = 0; ds < 4; ds++) {
        int c = (ds * 16 + lr) * 4 + h;
        int n = n0 + lg * 4;
        unsigned long long pk =
            (unsigned long long)f2bf(oacc[ds][0]) |
            ((unsigned long long)f2bf(oacc[ds][1]) << 16) |
            ((unsigned long long)f2bf(oacc[ds][2]) << 32) |
            ((unsigned long long)f2bf(oacc[ds][3]) << 48);
        *(unsigned long long*)&op[(size_t)c * Nn + n] = pk;
    }
}

// ---------------- finish: sum partials, normalize, transpose -> attnT[n][c] bf16 ----------------
__global__ __launch_bounds__(256) void k_finish(const unsigned short* __restrict__ opart,
                                                const float* __restrict__ denp,
                                                unsigned short* __restrict__ attnT) {
    __shared__ float t[64][65];
    const int cb = blockIdx.y * 64, nb = blockIdx.x * 64;
    const int tid = threadIdx.x;
    #pragma unroll
    for (int e = 0; e < 16; e++) {
        int idx = e * 256 + tid;
        int c_l = idx >> 6, n_l = idx & 63;
        int c = cb + c_l, n = nb + n_l;
        float s = 0.f;
        #pragma unroll
        for (int y = 0; y < 4; y++)
            s += bf2f(opart[(size_t)y * (Dm*Nn) + (size_t)c * Nn + n]);
        size_t row = (size_t)(c & 3) * Nn + n;
        float d = denp[row*4] + denp[row*4+1] + denp[row*4+2] + denp[row*4+3];
        t[c_l][n_l] = s / d;
    }
    __syncthreads();
    #pragma unroll
    for (int e = 0; e < 16; e++) {
        int idx = e * 256 + tid;
        int n_l = idx >> 6, c_l = idx & 63;
        attnT[(size_t)(nb + n_l) * 256 + cb + c_l] = f2bf(t[c_l][n_l]);
    }
}

extern "C" void kernel_launch(void* const* d_in, const int* in_sizes, int n_in,
                              void* d_out, int out_size, void* d_ws, size_t ws_size,
                              hipStream_t stream) {
    const float* x      = (const float*)d_in[0];
    const float* source = (const float*)d_in[1];
    const void*  mask   = d_in[3];
    const float* Wq = (const float*)d_in[4];  const float* bq = (const float*)d_in[5];
    const float* Wk = (const float*)d_in[6];  const float* bk = (const float*)d_in[7];
    const float* Wv = (const float*)d_in[8];  const float* bv = (const float*)d_in[9];
    const float* Wm = (const float*)d_in[10]; const float* bm = (const float*)d_in[11];
    const float* W1 = (const float*)d_in[12]; const float* b1 = (const float*)d_in[13];
    const float* W2 = (const float*)d_in[14]; const float* b2 = (const float*)d_in[15];

    float* y    = (float*)d_out;                // [256,4096]
    float* wout = y + (size_t)Dm * Nn;          // [4096,4096]

    char* ws = (char*)d_ws;
    int*      flag  = (int*)(ws + OFF_FLAG);
    unsigned* skey  = (unsigned*)(ws + OFF_SMIN);
    unsigned* kmax  = (unsigned*)(ws + OFF_KMAX);
    float*    mtarr = (float*)(ws + OFF_MT);
    float*    denp  = (float*)(ws + OFF_DENP);
    unsigned short* wb    = (unsigned short*)(ws + OFF_WB);
    unsigned char*  bits  = (unsigned char*)(ws + OFF_BITS);
    unsigned short* qb    = (unsigned short*)(ws + OFF_QB);
    unsigned short* kb    = (unsigned short*)(ws + OFF_KB);
    unsigned short* vb    = (unsigned short*)(ws + OFF_VB);
    unsigned short* hcat  = (unsigned short*)(ws + OFF_HCAT);
    unsigned short* attnT = (unsigned short*)(ws + OFF_ATTNT);
    unsigned short* xt    = (unsigned short*)(ws + OFF_XT);
    unsigned short* st    = (unsigned short*)(ws + OFF_ST);
    unsigned short* opart = (unsigned short*)(ws + OFF_OPART);
    unsigned short* h1t   = (unsigned short*)(ws + OFF_H1T);

    k_prep<<<dim3(128, 4, 2), 256, 0, stream>>>(x, source, xt, st, hcat,
                                                (const unsigned char*)mask, flag, kmax, skey);
    k_maskbits<<<8192, 256, 0, stream>>>(mask, flag, bits);
    k_wcast<<<2560, 256, 0, stream>>>(Wq, Wk, Wv, Wm, W1, W2, wb);

    k_qkv<<<dim3(64, 4, 3), 256, 0, stream>>>(wb, bq, bk, bv, xt, st, qb, kb, vb);

    k_knorm<<<dim3(16, 4), 256, 0, stream>>>(kb, kmax);
    k_qnorm<<<64, 256, 0, stream>>>(qb, kmax, mtarr);

    k_minwout<<<dim3(32, 16), 512, 0, stream>>>(qb, kb, skey, wout);
    k_wfix<<<4096, 256, 0, stream>>>(wout, (const unsigned long long*)bits, skey);

    k_pv<<<dim3(32, 16), 512, 0, stream>>>(qb, kb, vb, (const unsigned long long*)bits,
                                           skey, mtarr, denp, opart);
    k_finish<<<dim3(64, 4), 256, 0, stream>>>(opart, denp, attnT);

    k_mgemm<256><<<dim3(64, 4), 256, 0, stream>>>(wb + WOFF_M, bm, attnT, hcat, 3);
    k_mgemm<512><<<dim3(64, 8), 256, 0, stream>>>(wb + WOFF_1, b1, hcat, h1t, 4);
    k_mgemm<512><<<dim3(64, 4), 256, 0, stream>>>(wb + WOFF_2, b2, h1t, y, 0);
}

// Round 14
// 208.906 us; speedup vs baseline: 2.4466x; 1.0304x over previous
//
#include <hip/hip_runtime.h>
#include <hip/hip_bf16.h>
#include <math.h>

#define Dm 256
#define Hh 4
#define Nn 4096
#define Mq 4096

typedef __attribute__((ext_vector_type(8))) short bf16x8;
typedef __attribute__((ext_vector_type(4))) float f32x4;
typedef _Float16 __attribute__((ext_vector_type(4))) f16x4;
typedef __fp16 __attribute__((ext_vector_type(2))) h16x2;

#define MFMA_BF16(a,b,c) __builtin_amdgcn_mfma_f32_16x16x32_bf16(a,b,c,0,0,0)
#define MFMA_F16x16(a,b,c) __builtin_amdgcn_mfma_f32_16x16x16f16(a,b,c,0,0,0)

#define MB (1u<<20)
// ---- workspace layout (bytes) ----
#define OFF_FLAG  0
#define OFF_SMIN  64                  // unsigned key
#define OFF_KMAX  128                 // 4 u32
#define OFF_MT    4096                // 16384 f32 (64KB)
#define OFF_DENP  (128u<<10)          // 16384*4 f32 (256KB)
#define OFF_WB    (3u*MB/2)           // 655360 bf16 (1.25MB)
#define OFF_BITS  (3u*MB)             // 2MB bitmask
#define OFF_QB    (5u*MB)             // bf16 [h][n][64] 2MB
#define OFF_KB    (7u*MB)             // bf16 [h][m][64] swizzled 2MB
#define OFF_VB    (9u*MB)             // fp16 [h][dd][m] 2MB
#define OFF_HCAT  (11u*MB)            // bf16 [n][512] 4MB
#define OFF_ATTNT (15u*MB)            // bf16 [n][256] 2MB
// overlap region (xt/st die after k_qkv; opart dies before h1t written)
#define OFF_XT    (17u*MB)            // bf16 [n][256] 2MB
#define OFF_ST    (19u*MB)            // bf16 [n][256] 2MB
#define OFF_OPART (17u*MB)            // bf16 [4][c][n] 8MB -> ends 25MB
#define OFF_H1T   (17u*MB)            // bf16 [n][512] 4MB

#define WOFF_Q  0
#define WOFF_K  65536
#define WOFF_V  131072
#define WOFF_M  196608
#define WOFF_1  262144
#define WOFF_2  524288

__device__ __forceinline__ unsigned short f2bf(float x) {
    unsigned u = __float_as_uint(x);
    u += 0x7FFF + ((u >> 16) & 1);
    return (unsigned short)(u >> 16);
}
__device__ __forceinline__ float bf2f(unsigned short b) {
    return __uint_as_float(((unsigned)b) << 16);
}
__device__ __forceinline__ unsigned fkey(float f) {
    unsigned u = __float_as_uint(f);
    return (u & 0x80000000u) ? ~u : (u | 0x80000000u);
}
__device__ __forceinline__ float fdecode(unsigned k) {
    return (k & 0x80000000u) ? __uint_as_float(k ^ 0x80000000u) : __uint_as_float(~k);
}

// ---------------- transpose-cast + (block 0) mask dtype detect + inits ----------------
__global__ __launch_bounds__(256) void k_prep(const float* __restrict__ x,
                                              const float* __restrict__ source,
                                              unsigned short* __restrict__ xt,
                                              unsigned short* __restrict__ st,
                                              unsigned short* __restrict__ hcat,
                                              const unsigned char* __restrict__ maskb,
                                              int* __restrict__ flag,
                                              unsigned* __restrict__ kmax,
                                              unsigned* __restrict__ sminkey) {
    const int z = blockIdx.z;
    const float* src = z ? source : x;
    unsigned short* dst = z ? st : xt;
    unsigned short* dst2 = z ? nullptr : hcat;
    const int l = threadIdx.x & 63, g = threadIdx.x >> 6;
    const int c = blockIdx.y * 64 + l;
    const int n0 = blockIdx.x * 32 + g * 8;
    float4 v0 = *(const float4*)(src + (size_t)c * Nn + n0);
    float4 v1 = *(const float4*)(src + (size_t)c * Nn + n0 + 4);
    float vv[8] = {v0.x, v0.y, v0.z, v0.w, v1.x, v1.y, v1.z, v1.w};
    #pragma unroll
    for (int j = 0; j < 8; j++) {
        unsigned short b = f2bf(vv[j]);
        dst[(size_t)(n0 + j) * 256 + c] = b;
        if (dst2) dst2[(size_t)(n0 + j) * 512 + c] = b;
    }
    if (blockIdx.x == 0 && blockIdx.y == 0 && z == 0) {
        __shared__ int cnt[5];
        if (threadIdx.x < 5) cnt[threadIdx.x] = 0;
        if (threadIdx.x < 4) kmax[threadIdx.x] = 0u;
        if (threadIdx.x == 0) *sminkey = 0xFFFFFFFFu;
        __syncthreads();
        for (int i = threadIdx.x; i < 16384; i += 256) {
            unsigned char b = maskb[i];
            if (b) {
                atomicAdd(&cnt[i & 3], 1);
                if ((i & 7) == 4) atomicAdd(&cnt[4], 1);
            }
        }
        __syncthreads();
        if (threadIdx.x == 0) {
            int f;
            if (cnt[3] > 0 && cnt[0] == 0)        f = 3;  // f32
            else if (cnt[1] | cnt[2] | cnt[3])    f = 1;  // u8/bool
            else if (cnt[4] > 0)                  f = 0;  // i32
            else                                  f = 2;  // i64
            *flag = f;
        }
    }
}

// ---------------- mask -> bitmask ----------------
__global__ void k_maskbits(const void* __restrict__ mp, const int* __restrict__ flagp,
                           unsigned char* __restrict__ bits) {
    size_t i = (size_t)blockIdx.x * 256 + threadIdx.x;
    const int flag = *flagp;
    size_t base = i * 8;
    unsigned b = 0;
    if (flag == 1) {
        unsigned long long u = *(const unsigned long long*)((const unsigned char*)mp + base);
        #pragma unroll
        for (int j = 0; j < 8; j++) b |= (unsigned)(((u >> (8*j)) & 0xFFull) != 0ull) << j;
    } else if (flag == 0) {
        const int* p = (const int*)mp;
        #pragma unroll
        for (int j = 0; j < 8; j++) b |= (unsigned)(p[base + j] != 0) << j;
    } else if (flag == 3) {
        const float* p = (const float*)mp;
        #pragma unroll
        for (int j = 0; j < 8; j++) b |= (unsigned)(p[base + j] != 0.0f) << j;
    } else {
        const unsigned long long* p = (const unsigned long long*)mp;
        #pragma unroll
        for (int j = 0; j < 8; j++) b |= (unsigned)(p[base + j] != 0ull) << j;
    }
    bits[i] = (unsigned char)b;
}

// ---------------- cast all weights to bf16 ----------------
__global__ void k_wcast(const float* __restrict__ Wq, const float* __restrict__ Wk,
                        const float* __restrict__ Wv, const float* __restrict__ Wm,
                        const float* __restrict__ W1, const float* __restrict__ W2,
                        unsigned short* __restrict__ wb) {
    size_t i = (size_t)blockIdx.x * 256 + threadIdx.x;
    const float* s; size_t off;
    if      (i < 65536)               { s = Wq; off = i; }
    else if (i < 131072)              { s = Wk; off = i - 65536; }
    else if (i < 196608)              { s = Wv; off = i - 131072; }
    else if (i < 262144)              { s = Wm; off = i - 196608; }
    else if (i < 524288)              { s = W1; off = i - 262144; }
    else                              { s = W2; off = i - 524288; }
    wb[i] = f2bf(s[off]);
}

// ---------------- MFMA GEMM body (r7) ----------------
template<int KK>
__device__ __forceinline__ void gemm_body(const unsigned short* __restrict__ wb,
                                          const float* __restrict__ bias,
                                          const unsigned short* __restrict__ xt,
                                          void* __restrict__ out, int mode,
                                          int bx, int by) {
    const int tid = threadIdx.x, w = tid >> 6, lane = tid & 63;
    const int lg = lane >> 4, lr = lane & 15;
    const int o_base = by * 64 + w * 16;
    const int n_base = bx * 64;
    f32x4 acc[4];
    #pragma unroll
    for (int j = 0; j < 4; j++) acc[j] = (f32x4){0.f, 0.f, 0.f, 0.f};
    const unsigned short* wrow = wb + (size_t)(o_base + lr) * KK + lg * 8;
    const unsigned short* xrow = xt + (size_t)(n_base + lr) * KK + lg * 8;
    #pragma unroll
    for (int k0 = 0; k0 < KK; k0 += 32) {
        bf16x8 af = *(const bf16x8*)(wrow + k0);
        #pragma unroll
        for (int j = 0; j < 4; j++) {
            bf16x8 bfr = *(const bf16x8*)(xrow + (size_t)j * 16 * KK + k0);
            acc[j] = MFMA_BF16(af, bfr, acc[j]);
        }
    }
    float bv[4];
    #pragma unroll
    for (int r = 0; r < 4; r++) bv[r] = bias[o_base + lg * 4 + r];
    #pragma unroll
    for (int j = 0; j < 4; j++) {
        #pragma unroll
        for (int r = 0; r < 4; r++) {
            int o = o_base + lg * 4 + r;
            int n = n_base + j * 16 + lr;
            float v = acc[j][r] + bv[r];
            if (mode == 0) {
                ((float*)out)[(size_t)o * Nn + n] = v;
            } else if (mode == 1) {
                ((unsigned short*)out)[(((size_t)(o & 3)) * Nn + n) * 64 + (o >> 2)] = f2bf(v);
            } else if (mode == 2) {
                union { _Float16 h; unsigned short u; } cv; cv.h = (_Float16)v;
                ((unsigned short*)out)[(((size_t)(o & 3)) * 64 + (o >> 2)) * Mq + n] = cv.u;
            } else if (mode == 3) {
                ((unsigned short*)out)[(size_t)n * 512 + 256 + o] = f2bf(v);
            } else if (mode == 4) {
                ((unsigned short*)out)[(size_t)n * 512 + o] = f2bf(fmaxf(v, 0.f));
            } else {
                int dd = o >> 2, hh = o & 3, g = dd >> 3, pos = dd & 7;
                int slot = g ^ (n & 7);
                ((unsigned short*)out)[(((size_t)hh * Mq + n)) * 64 + slot * 8 + pos] = f2bf(v);
            }
        }
    }
}

template<int KK>
__global__ __launch_bounds__(256) void k_mgemm(const unsigned short* __restrict__ wb,
                                               const float* __restrict__ bias,
                                               const unsigned short* __restrict__ xt,
                                               void* __restrict__ out, int mode) {
    gemm_body<KK>(wb, bias, xt, out, mode, blockIdx.x, blockIdx.y);
}

__global__ __launch_bounds__(256) void k_qkv(const unsigned short* __restrict__ wb,
                                             const float* __restrict__ bq,
                                             const float* __restrict__ bk,
                                             const float* __restrict__ bv,
                                             const unsigned short* __restrict__ xt,
                                             const unsigned short* __restrict__ st,
                                             void* __restrict__ qb, void* __restrict__ kb,
                                             void* __restrict__ vb) {
    const int z = blockIdx.z;
    const float* bias = (z == 0) ? bq : ((z == 1) ? bk : bv);
    const unsigned short* X = (z == 0) ? xt : st;
    void* out = (z == 0) ? qb : ((z == 1) ? kb : vb);
    int mode = (z == 0) ? 1 : ((z == 1) ? 5 : 2);
    gemm_body<256>(wb + z * 65536, bias, X, out, mode, blockIdx.x, blockIdx.y);
}

// ---------------- norm-based row-max bound ----------------
__global__ __launch_bounds__(256) void k_knorm(const unsigned short* __restrict__ kb,
                                               unsigned* __restrict__ kmax) {
    const int h = blockIdx.y;
    const int m = blockIdx.x * 256 + threadIdx.x;
    const unsigned short* row = kb + ((size_t)(h * Mq + m) << 6);
    float s = 0.f;
    #pragma unroll
    for (int i = 0; i < 64; i++) { float v = bf2f(row[i]); s = fmaf(v, v, s); }
    __shared__ float red[256];
    red[threadIdx.x] = s;
    __syncthreads();
    for (int st = 128; st > 0; st >>= 1) {
        if (threadIdx.x < st) red[threadIdx.x] = fmaxf(red[threadIdx.x], red[threadIdx.x + st]);
        __syncthreads();
    }
    if (threadIdx.x == 0) atomicMax(kmax + h, __float_as_uint(red[0]));
}

__global__ __launch_bounds__(256) void k_qnorm(const unsigned short* __restrict__ qb,
                                               const unsigned* __restrict__ kmax,
                                               float* __restrict__ mtarr) {
    const int row = blockIdx.x * 256 + threadIdx.x;   // h*Nn + n
    const unsigned short* qr = qb + ((size_t)row << 6);
    float s = 0.f;
    #pragma unroll
    for (int i = 0; i < 64; i++) { float v = bf2f(qr[i]); s = fmaf(v, v, s); }
    float k2 = __uint_as_float(kmax[row >> 12]);
    mtarr[row] = sqrtf(s * k2) * 0.125f;   // |q|*|k|max/8 >= rowmax
}

// ---------------- fused: unmasked weights + global min (plain stores) ----------------
// grid (32, 16), 512 threads; per wave n16 all heads; m256 per block, LDS-staged K.
__global__ __launch_bounds__(512) void k_minwout(
    const unsigned short* __restrict__ qb, const unsigned short* __restrict__ kb,
    unsigned* __restrict__ sminkey, float* __restrict__ wout) {
    __shared__ unsigned short kbuf[2][8192];
    const int tid = threadIdx.x;
    const int w = tid >> 6, lane = tid & 63;
    const int lg = lane >> 4, lr = lane & 15;
    const int n0 = blockIdx.x * 128 + w * 16;
    const int m0 = blockIdx.y * 256;

    bf16x8 qf[4][2];
    #pragma unroll
    for (int h = 0; h < 4; h++)
        #pragma unroll
        for (int kh = 0; kh < 2; kh++)
            qf[h][kh] = *(const bf16x8*)(qb + (((size_t)h * Nn + n0 + lr) << 6) + kh*32 + lg*8);

    const int h0 = tid >> 8, q0 = tid & 255;
    const unsigned short* src0 = kb + (((size_t)h0 * Mq + m0) << 6) + q0 * 8;
    const unsigned short* src1 = kb + (((size_t)(h0 + 2) * Mq + m0) << 6) + q0 * 8;
    unsigned short* dst0 = &kbuf[0][h0 * 2048 + q0 * 8];
    unsigned short* dst1 = &kbuf[0][(h0 + 2) * 2048 + q0 * 8];

    float mn = INFINITY;

    bf16x8 r0 = *(const bf16x8*)(src0);
    bf16x8 r1 = *(const bf16x8*)(src1);
    *(bf16x8*)dst0 = r0;
    *(bf16x8*)dst1 = r1;
    __syncthreads();
    r0 = *(const bf16x8*)(src0 + 2048);
    r1 = *(const bf16x8*)(src1 + 2048);

    for (int t = 0; t < 8; t++) {
        const unsigned short* kB = &kbuf[t & 1][0];
        const int mch = m0 + t * 32;
        #pragma unroll
        for (int mi = 0; mi < 2; mi++) {
            const int rowoff = (mi * 16 + lr) * 64;
            f32x4 wsum = (f32x4){0.f, 0.f, 0.f, 0.f};
            #pragma unroll
            for (int h = 0; h < 4; h++) {
                bf16x8 a0 = *(const bf16x8*)(kB + h*2048 + rowoff + ((lg ^ (lr & 7)) << 3));
                bf16x8 a1 = *(const bf16x8*)(kB + h*2048 + rowoff + (((lg + 4) ^ (lr & 7)) << 3));
                f32x4 acc = (f32x4){0.f, 0.f, 0.f, 0.f};
                acc = MFMA_BF16(a0, qf[h][0], acc);
                acc = MFMA_BF16(a1, qf[h][1], acc);
                mn = fminf(mn, fminf(fminf(acc[0], acc[1]), fminf(acc[2], acc[3])));
                wsum += acc;
            }
            f32x4 wv;
            #pragma unroll
            for (int rr = 0; rr < 4; rr++) wv[rr] = wsum[rr] * 0.03125f;
            *(f32x4*)(wout + (size_t)(n0 + lr) * Mq + mch + mi * 16 + lg * 4) = wv;
        }
        if (t < 7) {
            *(bf16x8*)(dst0 + (((t + 1) & 1) ? 8192 : 0)) = r0;
            *(bf16x8*)(dst1 + (((t + 1) & 1) ? 8192 : 0)) = r1;
        }
        __syncthreads();
        if (t < 6) {
            r0 = *(const bf16x8*)(src0 + (size_t)(t + 2) * 2048);
            r1 = *(const bf16x8*)(src1 + (size_t)(t + 2) * 2048);
        }
    }

    for (int off = 1; off < 64; off <<= 1) mn = fminf(mn, __shfl_xor(mn, off));
    __shared__ float wmin[8];
    if (lane == 0) wmin[w] = mn;
    __syncthreads();
    if (tid == 0) {
        float m2 = wmin[0];
        #pragma unroll
        for (int i = 1; i < 8; i++) m2 = fminf(m2, wmin[i]);
        atomicMin(sminkey, fkey(m2 * 0.125f));
    }
}

// ---------------- flash PV (r7) + per-block wout mask-fix ----------------
// grid (32, 16=h4*mb4), 512 thr, 8 waves x n16, full dd.
__global__ __launch_bounds__(512) void k_pv(
    const unsigned short* __restrict__ qb, const unsigned short* __restrict__ kb,
    const unsigned short* __restrict__ vbh,
    const unsigned long long* __restrict__ bits,
    const unsigned* __restrict__ skey, const float* __restrict__ mtarr,
    float* __restrict__ denp, unsigned short* __restrict__ opart,
    float* __restrict__ wout) {
    __shared__ unsigned short kbuf[2][4096];   // [buf][m64][64] bf16 16KB
    __shared__ unsigned short vbuf[2][4096];   // [buf][(mi4 ds4)16 lr][slot4][4] f16 16KB
    const int tid = threadIdx.x;
    const int w = tid >> 6, lane = tid & 63;
    const int lg = lane >> 4, lr = lane & 15;
    const int h = blockIdx.y & 3, mb = blockIdx.y >> 2;
    const int n0 = blockIdx.x * 128 + w * 16;
    const int m0 = mb * 1024;
    const float smin = fdecode(*skey);
    const float sminc = fmaxf(smin, 0.f);

    bf16x8 qf0 = *(const bf16x8*)(qb + (((size_t)h * Nn + n0 + lr) << 6) + lg*8);
    bf16x8 qf1 = *(const bf16x8*)(qb + (((size_t)h * Nn + n0 + lr) << 6) + 32 + lg*8);
    float mtE = mtarr[(size_t)h * Nn + n0 + lr] + sminc;
    const float cT = -mtE * 1.44269504f;
    const float cF = cT + smin * 1.44269504f;

    f32x4 oacc[4];
    #pragma unroll
    for (int ds = 0; ds < 4; ds++) oacc[ds] = (f32x4){0.f, 0.f, 0.f, 0.f};
    float dsum = 0.f;

    const unsigned short* ksrc = kb + (((size_t)h * Mq + m0) << 6) + tid * 8;
    const int vdd = tid >> 3, vj = tid & 7;
    const unsigned short* vsrc = vbh + (size_t)(h * 64 + vdd) * Mq + m0 + vj * 8;
    const int vds = vdd >> 4, vlr = vdd & 15, vmi = vj >> 1;
    const int vswz = (vlr >> 2) & 3;
    const int vbase = ((vmi * 4 + vds) * 16 + vlr) * 4;
    const int vdst0 = (vbase + (((vj & 1) * 2 + 0) ^ vswz)) * 4;
    const int vdst1 = (vbase + (((vj & 1) * 2 + 1) ^ vswz)) * 4;

    union { bf16x8 v; unsigned long long q[2]; } rv;
    bf16x8 rk = *(const bf16x8*)(ksrc);
    rv.v = *(const bf16x8*)(vsrc);
    *(bf16x8*)&kbuf[0][tid * 8] = rk;
    *(unsigned long long*)&vbuf[0][vdst0] = rv.q[0];
    *(unsigned long long*)&vbuf[0][vdst1] = rv.q[1];
    __syncthreads();
    rk = *(const bf16x8*)(ksrc + 4096);
    rv.v = *(const bf16x8*)(vsrc + 64);

    const unsigned long long* brow = bits + (((size_t)(n0 + lr)) << 6) + (m0 >> 6);
    const int kslot0 = (lg ^ (lr & 7)) << 3;
    const int kslot1 = ((lg + 4) ^ (lr & 7)) << 3;
    const int vrslot = (lg ^ ((lr >> 2) & 3)) * 4;

    for (int t = 0; t < 16; t++) {
        const unsigned short* kB = &kbuf[t & 1][0];
        const unsigned short* vB = &vbuf[t & 1][0];
        unsigned long long bw = brow[t];
        #pragma unroll
        for (int mi = 0; mi < 4; mi++) {
            const int rowoff = (mi * 16 + lr) * 64;
            bf16x8 a0 = *(const bf16x8*)(kB + rowoff + kslot0);
            bf16x8 a1 = *(const bf16x8*)(kB + rowoff + kslot1);
            f16x4 vf[4];
            #pragma unroll
            for (int ds = 0; ds < 4; ds++)
                vf[ds] = *(const f16x4*)&vB[((mi * 4 + ds) * 16 + lr) * 16 + vrslot];
            f32x4 acc = (f32x4){0.f, 0.f, 0.f, 0.f};
            acc = MFMA_BF16(a0, qf0, acc);
            acc = MFMA_BF16(a1, qf1, acc);
            const int shb = mi * 16 + lg * 4;
            float p0 = exp2f(fmaf(acc[0], 0.18033688f, ((bw >> (shb + 0)) & 1ull) ? cT : cF));
            float p1 = exp2f(fmaf(acc[1], 0.18033688f, ((bw >> (shb + 1)) & 1ull) ? cT : cF));
            float p2 = exp2f(fmaf(acc[2], 0.18033688f, ((bw >> (shb + 2)) & 1ull) ? cT : cF));
            float p3 = exp2f(fmaf(acc[3], 0.18033688f, ((bw >> (shb + 3)) & 1ull) ? cT : cF));
            dsum += (p0 + p1) + (p2 + p3);
            union { h16x2 h2[2]; f16x4 f4; } pu;
            pu.h2[0] = __builtin_amdgcn_cvt_pkrtz(p0, p1);
            pu.h2[1] = __builtin_amdgcn_cvt_pkrtz(p2, p3);
            f16x4 pf = pu.f4;
            #pragma unroll
            for (int ds = 0; ds < 4; ds++)
                oacc[ds] = MFMA_F16x16(pf, vf[ds], oacc[ds]);
        }
        if (t < 15) {
            *(bf16x8*)&kbuf[(t + 1) & 1][tid * 8] = rk;
            *(unsigned long long*)&vbuf[(t + 1) & 1][vdst0] = rv.q[0];
            *(unsigned long long*)&vbuf[(t + 1) & 1][vdst1] = rv.q[1];
        }
        __syncthreads();
        if (t < 14) {
            rk = *(const bf16x8*)(ksrc + (size_t)(t + 2) * 4096);
            rv.v = *(const bf16x8*)(vsrc + (size_t)(t + 2) * 64);
        }
    }

    dsum += __shfl_xor(dsum, 16);
    dsum += __shfl_xor(dsum, 32);
    if (lane < 16)
        denp[((size_t)h * Nn + n0 + lane) * 4 + mb] = dsum;

    unsigned short* op = opart + (size_t)mb * (Dm * Nn);
    #pragma unroll
    for (int ds = 0; ds < 4; ds++) {
        int c = (ds * 16 + lr) * 4 + h;
        int n = n0 + lg * 4;
        unsigned long long pk =
            (unsigned long long)f2bf(oacc[ds][0]) |
            ((unsigned long long)f2bf(oacc[ds][1]) << 16) |
            ((unsigned long long)f2bf(oacc[ds][2]) << 32) |
            ((unsigned long long)f2bf(oacc[ds][3]) << 48);
        *(unsigned long long*)&op[(size_t)c * Nn + n] = pk;
    }

    // ---- wout mask-fix: this block fixes rows [nb*128 + h*32, +32) x [m0, m0+1024) ----
    {
        const int nbase = blockIdx.x * 128 + h * 32;
        // 32 rows x 256 f32x4-groups = 8192 groups / 512 threads = 16 iters
        for (int e = 0; e < 16; e++) {
            int gid = e * 512 + tid;
            int nl = gid >> 8;            // 0..31
            int mg = gid & 255;           // group of 4 within 1024
            int n = nbase + nl;
            int m4 = m0 + mg * 4;
            unsigned long long bwf = bits[(((size_t)n) << 6) + (m4 >> 6)];
            unsigned nib = (unsigned)(bwf >> (m4 & 63)) & 0xFu;
            if (nib == 0xFu) continue;
            f32x4* p = (f32x4*)(wout + (size_t)n * Mq + m4);
            f32x4 v = *p;
            if (!(nib & 1u)) v[0] += smin;
            if (!(nib & 2u)) v[1] += smin;
            if (!(nib & 4u)) v[2] += smin;
            if (!(nib & 8u)) v[3] += smin;
            *p = v;
        }
    }
}

// ---------------- finish: sum partials, normalize, transpose -> attnT[n][c] bf16 ----------------
__global__ __launch_bounds__(256) void k_finish(const unsigned short* __restrict__ opart,
                                                const float* __restrict__ denp,
                                                unsigned short* __restrict__ attnT) {
    __shared__ float t[64][65];
    const int cb = blockIdx.y * 64, nb = blockIdx.x * 64;
    const int tid = threadIdx.x;
    #pragma unroll
    for (int e = 0; e < 16; e++) {
        int idx = e * 256 + tid;
        int c_l = idx >> 6, n_l = idx & 63;
        int c = cb + c_l, n = nb + n_l;
        float s = 0.f;
        #pragma unroll
        for (int y = 0; y < 4; y++)
            s += bf2f(opart[(size_t)y * (Dm*Nn) + (size_t)c * Nn + n]);
        size_t row = (size_t)(c & 3) * Nn + n;
        float d = denp[row*4] + denp[row*4+1] + denp[row*4+2] + denp[row*4+3];
        t[c_l][n_l] = s / d;
    }
    __syncthreads();
    #pragma unroll
    for (int e = 0; e < 16; e++) {
        int idx = e * 256 + tid;
        int n_l = idx >> 6, c_l = idx & 63;
        attnT[(size_t)(nb + n_l) * 256 + cb + c_l] = f2bf(t[c_l][n_l]);
    }
}

extern "C" void kernel_launch(void* const* d_in, const int* in_sizes, int n_in,
                              void* d_out, int out_size, void* d_ws, size_t ws_size,
                              hipStream_t stream) {
    const float* x      = (const float*)d_in[0];
    const float* source = (const float*)d_in[1];
    const void*  mask   = d_in[3];
    const float* Wq = (const float*)d_in[4];  const float* bq = (const float*)d_in[5];
    const float* Wk = (const float*)d_in[6];  const float* bk = (const float*)d_in[7];
    const float* Wv = (const float*)d_in[8];  const float* bv = (const float*)d_in[9];
    const float* Wm = (const float*)d_in[10]; const float* bm = (const float*)d_in[11];
    const float* W1 = (const float*)d_in[12]; const float* b1 = (const float*)d_in[13];
    const float* W2 = (const float*)d_in[14]; const float* b2 = (const float*)d_in[15];

    float* y    = (float*)d_out;                // [256,4096]
    float* wout = y + (size_t)Dm * Nn;          // [4096,4096]

    char* ws = (char*)d_ws;
    int*      flag  = (int*)(ws + OFF_FLAG);
    unsigned* skey  = (unsigned*)(ws + OFF_SMIN);
    unsigned* kmax  = (unsigned*)(ws + OFF_KMAX);
    float*    mtarr = (float*)(ws + OFF_MT);
    float*    denp  = (float*)(ws + OFF_DENP);
    unsigned short* wb    = (unsigned short*)(ws + OFF_WB);
    unsigned char*  bits  = (unsigned char*)(ws + OFF_BITS);
    unsigned short* qb    = (unsigned short*)(ws + OFF_QB);
    unsigned short* kb    = (unsigned short*)(ws + OFF_KB);
    unsigned short* vb    = (unsigned short*)(ws + OFF_VB);
    unsigned short* hcat  = (unsigned short*)(ws + OFF_HCAT);
    unsigned short* attnT = (unsigned short*)(ws + OFF_ATTNT);
    unsigned short* xt    = (unsigned short*)(ws + OFF_XT);
    unsigned short* st    = (unsigned short*)(ws + OFF_ST);
    unsigned short* opart = (unsigned short*)(ws + OFF_OPART);
    unsigned short* h1t   = (unsigned short*)(ws + OFF_H1T);

    k_prep<<<dim3(128, 4, 2), 256, 0, stream>>>(x, source, xt, st, hcat,
                                                (const unsigned char*)mask, flag, kmax, skey);
    k_maskbits<<<8192, 256, 0, stream>>>(mask, flag, bits);
    k_wcast<<<2560, 256, 0, stream>>>(Wq, Wk, Wv, Wm, W1, W2, wb);

    k_qkv<<<dim3(64, 4, 3), 256, 0, stream>>>(wb, bq, bk, bv, xt, st, qb, kb, vb);

    k_knorm<<<dim3(16, 4), 256, 0, stream>>>(kb, kmax);
    k_qnorm<<<64, 256, 0, stream>>>(qb, kmax, mtarr);

    k_minwout<<<dim3(32, 16), 512, 0, stream>>>(qb, kb, skey, wout);

    k_pv<<<dim3(32, 16), 512, 0, stream>>>(qb, kb, vb, (const unsigned long long*)bits,
                                           skey, mtarr, denp, opart, wout);
    k_finish<<<dim3(64, 4), 256, 0, stream>>>(opart, denp, attnT);

    k_mgemm<256><<<dim3(64, 4), 256, 0, stream>>>(wb + WOFF_M, bm, attnT, hcat, 3);
    k_mgemm<512><<<dim3(64, 8), 256, 0, stream>>>(wb + WOFF_1, b1, hcat, h1t, 4);
    k_mgemm<512><<<dim3(64, 4), 256, 0, stream>>>(wb + WOFF_2, b2, h1t, y, 0);
}

// Round 15
// 196.807 us; speedup vs baseline: 2.5970x; 1.0615x over previous
//
#include <hip/hip_runtime.h>
#include <hip/hip_bf16.h>
#include <math.h>

#define Dm 256
#define Hh 4
#define Nn 4096
#define Mq 4096

typedef __attribute__((ext_vector_type(8))) short bf16x8;
typedef __attribute__((ext_vector_type(4))) float f32x4;
typedef _Float16 __attribute__((ext_vector_type(4))) f16x4;
typedef __fp16 __attribute__((ext_vector_type(2))) h16x2;

#define MFMA_BF16(a,b,c) __builtin_amdgcn_mfma_f32_16x16x32_bf16(a,b,c,0,0,0)
#define MFMA_F16x16(a,b,c) __builtin_amdgcn_mfma_f32_16x16x16f16(a,b,c,0,0,0)

#define MB (1u<<20)
// ---- workspace layout (bytes) ----
#define OFF_FLAG  0
#define OFF_SMIN  64                  // unsigned key (atomicMin, fkey-encoded)
#define OFF_KMAX  128                 // 4 u32
#define OFF_MT    4096                // 16384 f32 (64KB)
#define OFF_DENP  (128u<<10)          // 16384*4 f32 (256KB)
#define OFF_WB    (3u*MB/2)           // 655360 bf16 (1.25MB)
#define OFF_BITS  (3u*MB)             // 2MB bitmask
#define OFF_QB    (5u*MB)             // bf16 [h][n][64] 2MB
#define OFF_KB    (7u*MB)             // bf16 [h][m][64] swizzled 2MB
#define OFF_VB    (9u*MB)             // fp16 [h][dd][m] 2MB
#define OFF_HCAT  (11u*MB)            // bf16 [n][512] 4MB
#define OFF_ATTNT (15u*MB)            // bf16 [n][256] 2MB
// overlap region (xt/st die after k_qkv; opart dies before h1t written)
#define OFF_XT    (17u*MB)            // bf16 [n][256] 2MB
#define OFF_ST    (19u*MB)            // bf16 [n][256] 2MB
#define OFF_OPART (17u*MB)            // bf16 [4][c][n] 8MB -> ends 25MB
#define OFF_H1T   (17u*MB)            // bf16 [n][512] 4MB

#define WOFF_Q  0
#define WOFF_K  65536
#define WOFF_V  131072
#define WOFF_M  196608
#define WOFF_1  262144
#define WOFF_2  524288

__device__ __forceinline__ unsigned short f2bf(float x) {
    unsigned u = __float_as_uint(x);
    u += 0x7FFF + ((u >> 16) & 1);
    return (unsigned short)(u >> 16);
}
__device__ __forceinline__ float bf2f(unsigned short b) {
    return __uint_as_float(((unsigned)b) << 16);
}
__device__ __forceinline__ unsigned fkey(float f) {
    unsigned u = __float_as_uint(f);
    return (u & 0x80000000u) ? ~u : (u | 0x80000000u);
}
__device__ __forceinline__ float fdecode(unsigned k) {
    return (k & 0x80000000u) ? __uint_as_float(k ^ 0x80000000u) : __uint_as_float(~k);
}

// ---------------- transpose-cast + (block 0) mask dtype detect + inits ----------------
__global__ __launch_bounds__(256) void k_prep(const float* __restrict__ x,
                                              const float* __restrict__ source,
                                              unsigned short* __restrict__ xt,
                                              unsigned short* __restrict__ st,
                                              unsigned short* __restrict__ hcat,
                                              const unsigned char* __restrict__ maskb,
                                              int* __restrict__ flag,
                                              unsigned* __restrict__ kmax,
                                              unsigned* __restrict__ sminkey) {
    const int z = blockIdx.z;
    const float* src = z ? source : x;
    unsigned short* dst = z ? st : xt;
    unsigned short* dst2 = z ? nullptr : hcat;
    const int l = threadIdx.x & 63, g = threadIdx.x >> 6;
    const int c = blockIdx.y * 64 + l;
    const int n0 = blockIdx.x * 32 + g * 8;
    float4 v0 = *(const float4*)(src + (size_t)c * Nn + n0);
    float4 v1 = *(const float4*)(src + (size_t)c * Nn + n0 + 4);
    float vv[8] = {v0.x, v0.y, v0.z, v0.w, v1.x, v1.y, v1.z, v1.w};
    #pragma unroll
    for (int j = 0; j < 8; j++) {
        unsigned short b = f2bf(vv[j]);
        dst[(size_t)(n0 + j) * 256 + c] = b;
        if (dst2) dst2[(size_t)(n0 + j) * 512 + c] = b;
    }
    if (blockIdx.x == 0 && blockIdx.y == 0 && z == 0) {
        __shared__ int cnt[5];
        if (threadIdx.x < 5) cnt[threadIdx.x] = 0;
        if (threadIdx.x < 4) kmax[threadIdx.x] = 0u;
        if (threadIdx.x == 0) *sminkey = 0xFFFFFFFFu;
        __syncthreads();
        for (int i = threadIdx.x; i < 16384; i += 256) {
            unsigned char b = maskb[i];
            if (b) {
                atomicAdd(&cnt[i & 3], 1);
                if ((i & 7) == 4) atomicAdd(&cnt[4], 1);
            }
        }
        __syncthreads();
        if (threadIdx.x == 0) {
            int f;
            if (cnt[3] > 0 && cnt[0] == 0)        f = 3;  // f32
            else if (cnt[1] | cnt[2] | cnt[3])    f = 1;  // u8/bool
            else if (cnt[4] > 0)                  f = 0;  // i32
            else                                  f = 2;  // i64
            *flag = f;
        }
    }
}

// ---------------- mask -> bitmask ----------------
__global__ void k_maskbits(const void* __restrict__ mp, const int* __restrict__ flagp,
                           unsigned char* __restrict__ bits) {
    size_t i = (size_t)blockIdx.x * 256 + threadIdx.x;
    const int flag = *flagp;
    size_t base = i * 8;
    unsigned b = 0;
    if (flag == 1) {
        unsigned long long u = *(const unsigned long long*)((const unsigned char*)mp + base);
        #pragma unroll
        for (int j = 0; j < 8; j++) b |= (unsigned)(((u >> (8*j)) & 0xFFull) != 0ull) << j;
    } else if (flag == 0) {
        const int* p = (const int*)mp;
        #pragma unroll
        for (int j = 0; j < 8; j++) b |= (unsigned)(p[base + j] != 0) << j;
    } else if (flag == 3) {
        const float* p = (const float*)mp;
        #pragma unroll
        for (int j = 0; j < 8; j++) b |= (unsigned)(p[base + j] != 0.0f) << j;
    } else {
        const unsigned long long* p = (const unsigned long long*)mp;
        #pragma unroll
        for (int j = 0; j < 8; j++) b |= (unsigned)(p[base + j] != 0ull) << j;
    }
    bits[i] = (unsigned char)b;
}

// ---------------- cast all weights to bf16 ----------------
__global__ void k_wcast(const float* __restrict__ Wq, const float* __restrict__ Wk,
                        const float* __restrict__ Wv, const float* __restrict__ Wm,
                        const float* __restrict__ W1, const float* __restrict__ W2,
                        unsigned short* __restrict__ wb) {
    size_t i = (size_t)blockIdx.x * 256 + threadIdx.x;
    const float* s; size_t off;
    if      (i < 65536)               { s = Wq; off = i; }
    else if (i < 131072)              { s = Wk; off = i - 65536; }
    else if (i < 196608)              { s = Wv; off = i - 131072; }
    else if (i < 262144)              { s = Wm; off = i - 196608; }
    else if (i < 524288)              { s = W1; off = i - 262144; }
    else                              { s = W2; off = i - 524288; }
    wb[i] = f2bf(s[off]);
}

// ---------------- MFMA GEMM body (r7) ----------------
template<int KK>
__device__ __forceinline__ void gemm_body(const unsigned short* __restrict__ wb,
                                          const float* __restrict__ bias,
                                          const unsigned short* __restrict__ xt,
                                          void* __restrict__ out, int mode,
                                          int bx, int by) {
    const int tid = threadIdx.x, w = tid >> 6, lane = tid & 63;
    const int lg = lane >> 4, lr = lane & 15;
    const int o_base = by * 64 + w * 16;
    const int n_base = bx * 64;
    f32x4 acc[4];
    #pragma unroll
    for (int j = 0; j < 4; j++) acc[j] = (f32x4){0.f, 0.f, 0.f, 0.f};
    const unsigned short* wrow = wb + (size_t)(o_base + lr) * KK + lg * 8;
    const unsigned short* xrow = xt + (size_t)(n_base + lr) * KK + lg * 8;
    #pragma unroll
    for (int k0 = 0; k0 < KK; k0 += 32) {
        bf16x8 af = *(const bf16x8*)(wrow + k0);
        #pragma unroll
        for (int j = 0; j < 4; j++) {
            bf16x8 bfr = *(const bf16x8*)(xrow + (size_t)j * 16 * KK + k0);
            acc[j] = MFMA_BF16(af, bfr, acc[j]);
        }
    }
    float bv[4];
    #pragma unroll
    for (int r = 0; r < 4; r++) bv[r] = bias[o_base + lg * 4 + r];
    #pragma unroll
    for (int j = 0; j < 4; j++) {
        #pragma unroll
        for (int r = 0; r < 4; r++) {
            int o = o_base + lg * 4 + r;
            int n = n_base + j * 16 + lr;
            float v = acc[j][r] + bv[r];
            if (mode == 0) {
                ((float*)out)[(size_t)o * Nn + n] = v;
            } else if (mode == 1) {
                ((unsigned short*)out)[(((size_t)(o & 3)) * Nn + n) * 64 + (o >> 2)] = f2bf(v);
            } else if (mode == 2) {
                union { _Float16 h; unsigned short u; } cv; cv.h = (_Float16)v;
                ((unsigned short*)out)[(((size_t)(o & 3)) * 64 + (o >> 2)) * Mq + n] = cv.u;
            } else if (mode == 3) {
                ((unsigned short*)out)[(size_t)n * 512 + 256 + o] = f2bf(v);
            } else if (mode == 4) {
                ((unsigned short*)out)[(size_t)n * 512 + o] = f2bf(fmaxf(v, 0.f));
            } else {
                int dd = o >> 2, hh = o & 3, g = dd >> 3, pos = dd & 7;
                int slot = g ^ (n & 7);
                ((unsigned short*)out)[(((size_t)hh * Mq + n)) * 64 + slot * 8 + pos] = f2bf(v);
            }
        }
    }
}

template<int KK>
__global__ __launch_bounds__(256) void k_mgemm(const unsigned short* __restrict__ wb,
                                               const float* __restrict__ bias,
                                               const unsigned short* __restrict__ xt,
                                               void* __restrict__ out, int mode) {
    gemm_body<KK>(wb, bias, xt, out, mode, blockIdx.x, blockIdx.y);
}

__global__ __launch_bounds__(256) void k_qkv(const unsigned short* __restrict__ wb,
                                             const float* __restrict__ bq,
                                             const float* __restrict__ bk,
                                             const float* __restrict__ bv,
                                             const unsigned short* __restrict__ xt,
                                             const unsigned short* __restrict__ st,
                                             void* __restrict__ qb, void* __restrict__ kb,
                                             void* __restrict__ vb) {
    const int z = blockIdx.z;
    const float* bias = (z == 0) ? bq : ((z == 1) ? bk : bv);
    const unsigned short* X = (z == 0) ? xt : st;
    void* out = (z == 0) ? qb : ((z == 1) ? kb : vb);
    int mode = (z == 0) ? 1 : ((z == 1) ? 5 : 2);
    gemm_body<256>(wb + z * 65536, bias, X, out, mode, blockIdx.x, blockIdx.y);
}

// ---------------- norm-based row-max bound ----------------
__global__ __launch_bounds__(256) void k_knorm(const unsigned short* __restrict__ kb,
                                               unsigned* __restrict__ kmax) {
    const int h = blockIdx.y;
    const int m = blockIdx.x * 256 + threadIdx.x;
    const unsigned short* row = kb + ((size_t)(h * Mq + m) << 6);
    float s = 0.f;
    #pragma unroll
    for (int i = 0; i < 64; i++) { float v = bf2f(row[i]); s = fmaf(v, v, s); }
    __shared__ float red[256];
    red[threadIdx.x] = s;
    __syncthreads();
    for (int st = 128; st > 0; st >>= 1) {
        if (threadIdx.x < st) red[threadIdx.x] = fmaxf(red[threadIdx.x], red[threadIdx.x + st]);
        __syncthreads();
    }
    if (threadIdx.x == 0) atomicMax(kmax + h, __float_as_uint(red[0]));
}

__global__ __launch_bounds__(256) void k_qnorm(const unsigned short* __restrict__ qb,
                                               const unsigned* __restrict__ kmax,
                                               float* __restrict__ mtarr) {
    const int row = blockIdx.x * 256 + threadIdx.x;   // h*Nn + n
    const unsigned short* qr = qb + ((size_t)row << 6);
    float s = 0.f;
    #pragma unroll
    for (int i = 0; i < 64; i++) { float v = bf2f(qr[i]); s = fmaf(v, v, s); }
    float k2 = __uint_as_float(kmax[row >> 12]);
    mtarr[row] = sqrtf(s * k2) * 0.125f;   // |q|*|k|max/8 >= rowmax
}

// ---------------- global min of raw scores (r7 shape, atomicMin epilogue) ----------------
// grid (32, 16), 512 threads; per wave n16 all heads; m256 per block, LDS-staged K.
__global__ __launch_bounds__(512) void k_min(
    const unsigned short* __restrict__ qb, const unsigned short* __restrict__ kb,
    unsigned* __restrict__ sminkey) {
    __shared__ unsigned short kbuf[2][8192];   // [buf][h][m32][64] 32KB
    const int tid = threadIdx.x;
    const int w = tid >> 6, lane = tid & 63;
    const int lg = lane >> 4, lr = lane & 15;
    const int n0 = blockIdx.x * 128 + w * 16;
    const int m0 = blockIdx.y * 256;

    bf16x8 qf[4][2];
    #pragma unroll
    for (int h = 0; h < 4; h++)
        #pragma unroll
        for (int kh = 0; kh < 2; kh++)
            qf[h][kh] = *(const bf16x8*)(qb + (((size_t)h * Nn + n0 + lr) << 6) + kh*32 + lg*8);

    const int h0 = tid >> 8, q0 = tid & 255;
    const unsigned short* src0 = kb + (((size_t)h0 * Mq + m0) << 6) + q0 * 8;
    const unsigned short* src1 = kb + (((size_t)(h0 + 2) * Mq + m0) << 6) + q0 * 8;
    unsigned short* dst0 = &kbuf[0][h0 * 2048 + q0 * 8];
    unsigned short* dst1 = &kbuf[0][(h0 + 2) * 2048 + q0 * 8];

    float mn = INFINITY;

    bf16x8 r0 = *(const bf16x8*)(src0);
    bf16x8 r1 = *(const bf16x8*)(src1);
    *(bf16x8*)dst0 = r0;
    *(bf16x8*)dst1 = r1;
    __syncthreads();
    r0 = *(const bf16x8*)(src0 + 2048);
    r1 = *(const bf16x8*)(src1 + 2048);

    for (int t = 0; t < 8; t++) {
        const unsigned short* kB = &kbuf[t & 1][0];
        #pragma unroll
        for (int mi = 0; mi < 2; mi++) {
            const int rowoff = (mi * 16 + lr) * 64;
            #pragma unroll
            for (int h = 0; h < 4; h++) {
                bf16x8 a0 = *(const bf16x8*)(kB + h*2048 + rowoff + ((lg ^ (lr & 7)) << 3));
                bf16x8 a1 = *(const bf16x8*)(kB + h*2048 + rowoff + (((lg + 4) ^ (lr & 7)) << 3));
                f32x4 acc = (f32x4){0.f, 0.f, 0.f, 0.f};
                acc = MFMA_BF16(a0, qf[h][0], acc);
                acc = MFMA_BF16(a1, qf[h][1], acc);
                mn = fminf(mn, fminf(fminf(acc[0], acc[1]), fminf(acc[2], acc[3])));
            }
        }
        if (t < 7) {
            *(bf16x8*)(dst0 + (((t + 1) & 1) ? 8192 : 0)) = r0;
            *(bf16x8*)(dst1 + (((t + 1) & 1) ? 8192 : 0)) = r1;
        }
        __syncthreads();
        if (t < 6) {
            r0 = *(const bf16x8*)(src0 + (size_t)(t + 2) * 2048);
            r1 = *(const bf16x8*)(src1 + (size_t)(t + 2) * 2048);
        }
    }

    for (int off = 1; off < 64; off <<= 1) mn = fminf(mn, __shfl_xor(mn, off));
    __shared__ float wmin[8];
    if (lane == 0) wmin[w] = mn;
    __syncthreads();
    if (tid == 0) {
        float m2 = wmin[0];
        #pragma unroll
        for (int i = 1; i < 8; i++) m2 = fminf(m2, wmin[i]);
        atomicMin(sminkey, fkey(m2 * 0.125f));
    }
}

// ---------------- weights: full-K head-summed GEMM + masked epilogue (r7) ----------------
// grid (32, 16), 512 threads; m256 per block.
__global__ __launch_bounds__(512) void k_wout(
    const unsigned short* __restrict__ qb, const unsigned short* __restrict__ kb,
    const unsigned long long* __restrict__ bits,
    const unsigned* __restrict__ skey, float* __restrict__ wout) {
    __shared__ unsigned short kbuf[2][8192];
    const int tid = threadIdx.x;
    const int w = tid >> 6, lane = tid & 63;
    const int lg = lane >> 4, lr = lane & 15;
    const int n0 = blockIdx.x * 128 + w * 16;
    const int m0 = blockIdx.y * 256;
    const float smin = fdecode(*skey);

    bf16x8 qf[4][2];
    #pragma unroll
    for (int h = 0; h < 4; h++)
        #pragma unroll
        for (int kh = 0; kh < 2; kh++)
            qf[h][kh] = *(const bf16x8*)(qb + (((size_t)h * Nn + n0 + lr) << 6) + kh*32 + lg*8);

    const int h0 = tid >> 8, q0 = tid & 255;
    const unsigned short* src0 = kb + (((size_t)h0 * Mq + m0) << 6) + q0 * 8;
    const unsigned short* src1 = kb + (((size_t)(h0 + 2) * Mq + m0) << 6) + q0 * 8;
    unsigned short* dst0 = &kbuf[0][h0 * 2048 + q0 * 8];
    unsigned short* dst1 = &kbuf[0][(h0 + 2) * 2048 + q0 * 8];

    const unsigned long long* brow = bits + (((size_t)(n0 + lr)) << 6) + (m0 >> 6);
    unsigned long long bw = 0ull;

    bf16x8 r0 = *(const bf16x8*)(src0);
    bf16x8 r1 = *(const bf16x8*)(src1);
    *(bf16x8*)dst0 = r0;
    *(bf16x8*)dst1 = r1;
    __syncthreads();
    r0 = *(const bf16x8*)(src0 + 2048);
    r1 = *(const bf16x8*)(src1 + 2048);

    for (int t = 0; t < 8; t++) {
        const unsigned short* kB = &kbuf[t & 1][0];
        const int mch = m0 + t * 32;
        if ((t & 1) == 0) bw = brow[t >> 1];
        #pragma unroll
        for (int mi = 0; mi < 2; mi++) {
            const int rowoff = (mi * 16 + lr) * 64;
            f32x4 accA = (f32x4){0.f, 0.f, 0.f, 0.f};
            f32x4 accB = (f32x4){0.f, 0.f, 0.f, 0.f};
            #pragma unroll
            for (int h = 0; h < 2; h++) {
                bf16x8 a0 = *(const bf16x8*)(kB + h*2048 + rowoff + ((lg ^ (lr & 7)) << 3));
                bf16x8 a1 = *(const bf16x8*)(kB + h*2048 + rowoff + (((lg + 4) ^ (lr & 7)) << 3));
                accA = MFMA_BF16(a0, qf[h][0], accA);
                accA = MFMA_BF16(a1, qf[h][1], accA);
            }
            #pragma unroll
            for (int h = 2; h < 4; h++) {
                bf16x8 a0 = *(const bf16x8*)(kB + h*2048 + rowoff + ((lg ^ (lr & 7)) << 3));
                bf16x8 a1 = *(const bf16x8*)(kB + h*2048 + rowoff + (((lg + 4) ^ (lr & 7)) << 3));
                accB = MFMA_BF16(a0, qf[h][0], accB);
                accB = MFMA_BF16(a1, qf[h][1], accB);
            }
            const int shb = (t & 1) * 32 + mi * 16 + lg * 4;
            f32x4 wv;
            #pragma unroll
            for (int rr = 0; rr < 4; rr++) {
                bool b = (bw >> (shb + rr)) & 1ull;
                wv[rr] = fmaf(accA[rr] + accB[rr], 0.03125f, b ? 0.f : smin);
            }
            *(f32x4*)(wout + (size_t)(n0 + lr) * Mq + mch + mi * 16 + lg * 4) = wv;
        }
        if (t < 7) {
            *(bf16x8*)(dst0 + (((t + 1) & 1) ? 8192 : 0)) = r0;
            *(bf16x8*)(dst1 + (((t + 1) & 1) ? 8192 : 0)) = r1;
        }
        __syncthreads();
        if (t < 6) {
            r0 = *(const bf16x8*)(src0 + (size_t)(t + 2) * 2048);
            r1 = *(const bf16x8*)(src1 + (size_t)(t + 2) * 2048);
        }
    }
}

// ---------------- flash PV (r7): grid (32, 16=h4*mb4), 512 thr, 8 waves x n16, full dd ----------------
__global__ __launch_bounds__(512) void k_pv(
    const unsigned short* __restrict__ qb, const unsigned short* __restrict__ kb,
    const unsigned short* __restrict__ vbh,
    const unsigned long long* __restrict__ bits,
    const unsigned* __restrict__ skey, const float* __restrict__ mtarr,
    float* __restrict__ denp, unsigned short* __restrict__ opart) {
    __shared__ unsigned short kbuf[2][4096];   // [buf][m64][64] bf16 16KB
    __shared__ unsigned short vbuf[2][4096];   // [buf][(mi4 ds4)16 lr][slot4][4] f16 16KB
    const int tid = threadIdx.x;
    const int w = tid >> 6, lane = tid & 63;
    const int lg = lane >> 4, lr = lane & 15;
    const int h = blockIdx.y & 3, mb = blockIdx.y >> 2;
    const int n0 = blockIdx.x * 128 + w * 16;
    const int m0 = mb * 1024;
    const float smin = fdecode(*skey);
    const float sminc = fmaxf(smin, 0.f);

    bf16x8 qf0 = *(const bf16x8*)(qb + (((size_t)h * Nn + n0 + lr) << 6) + lg*8);
    bf16x8 qf1 = *(const bf16x8*)(qb + (((size_t)h * Nn + n0 + lr) << 6) + 32 + lg*8);
    float mtE = mtarr[(size_t)h * Nn + n0 + lr] + sminc;
    const float cT = -mtE * 1.44269504f;
    const float cF = cT + smin * 1.44269504f;

    f32x4 oacc[4];
    #pragma unroll
    for (int ds = 0; ds < 4; ds++) oacc[ds] = (f32x4){0.f, 0.f, 0.f, 0.f};
    float dsum = 0.f;

    const unsigned short* ksrc = kb + (((size_t)h * Mq + m0) << 6) + tid * 8;
    const int vdd = tid >> 3, vj = tid & 7;
    const unsigned short* vsrc = vbh + (size_t)(h * 64 + vdd) * Mq + m0 + vj * 8;
    const int vds = vdd >> 4, vlr = vdd & 15, vmi = vj >> 1;
    const int vswz = (vlr >> 2) & 3;
    const int vbase = ((vmi * 4 + vds) * 16 + vlr) * 4;
    const int vdst0 = (vbase + (((vj & 1) * 2 + 0) ^ vswz)) * 4;
    const int vdst1 = (vbase + (((vj & 1) * 2 + 1) ^ vswz)) * 4;

    union { bf16x8 v; unsigned long long q[2]; } rv;
    bf16x8 rk = *(const bf16x8*)(ksrc);
    rv.v = *(const bf16x8*)(vsrc);
    *(bf16x8*)&kbuf[0][tid * 8] = rk;
    *(unsigned long long*)&vbuf[0][vdst0] = rv.q[0];
    *(unsigned long long*)&vbuf[0][vdst1] = rv.q[1];
    __syncthreads();
    rk = *(const bf16x8*)(ksrc + 4096);
    rv.v = *(const bf16x8*)(vsrc + 64);

    const unsigned long long* brow = bits + (((size_t)(n0 + lr)) << 6) + (m0 >> 6);
    const int kslot0 = (lg ^ (lr & 7)) << 3;
    const int kslot1 = ((lg + 4) ^ (lr & 7)) << 3;
    const int vrslot = (lg ^ ((lr >> 2) & 3)) * 4;

    for (int t = 0; t < 16; t++) {
        const unsigned short* kB = &kbuf[t & 1][0];
        const unsigned short* vB = &vbuf[t & 1][0];
        unsigned long long bw = brow[t];
        #pragma unroll
        for (int mi = 0; mi < 4; mi++) {
            const int rowoff = (mi * 16 + lr) * 64;
            bf16x8 a0 = *(const bf16x8*)(kB + rowoff + kslot0);
            bf16x8 a1 = *(const bf16x8*)(kB + rowoff + kslot1);
            f16x4 vf[4];
            #pragma unroll
            for (int ds = 0; ds < 4; ds++)
                vf[ds] = *(const f16x4*)&vB[((mi * 4 + ds) * 16 + lr) * 16 + vrslot];
            f32x4 acc = (f32x4){0.f, 0.f, 0.f, 0.f};
            acc = MFMA_BF16(a0, qf0, acc);
            acc = MFMA_BF16(a1, qf1, acc);
            const int shb = mi * 16 + lg * 4;
            float p0 = exp2f(fmaf(acc[0], 0.18033688f, ((bw >> (shb + 0)) & 1ull) ? cT : cF));
            float p1 = exp2f(fmaf(acc[1], 0.18033688f, ((bw >> (shb + 1)) & 1ull) ? cT : cF));
            float p2 = exp2f(fmaf(acc[2], 0.18033688f, ((bw >> (shb + 2)) & 1ull) ? cT : cF));
            float p3 = exp2f(fmaf(acc[3], 0.18033688f, ((bw >> (shb + 3)) & 1ull) ? cT : cF));
            dsum += (p0 + p1) + (p2 + p3);
            union { h16x2 h2[2]; f16x4 f4; } pu;
            pu.h2[0] = __builtin_amdgcn_cvt_pkrtz(p0, p1);
            pu.h2[1] = __builtin_amdgcn_cvt_pkrtz(p2, p3);
            f16x4 pf = pu.f4;
            #pragma unroll
            for (int ds = 0; ds < 4; ds++)
                oacc[ds] = MFMA_F16x16(pf, vf[ds], oacc[ds]);
        }
        if (t < 15) {
            *(bf16x8*)&kbuf[(t + 1) & 1][tid * 8] = rk;
            *(unsigned long long*)&vbuf[(t + 1) & 1][vdst0] = rv.q[0];
            *(unsigned long long*)&vbuf[(t + 1) & 1][vdst1] = rv.q[1];
        }
        __syncthreads();
        if (t < 14) {
            rk = *(const bf16x8*)(ksrc + (size_t)(t + 2) * 4096);
            rv.v = *(const bf16x8*)(vsrc + (size_t)(t + 2) * 64);
        }
    }

    dsum += __shfl_xor(dsum, 16);
    dsum += __shfl_xor(dsum, 32);
    if (lane < 16)
        denp[((size_t)h * Nn + n0 + lane) * 4 + mb] = dsum;

    unsigned short* op = opart + (size_t)mb * (Dm * Nn);
    #pragma unroll
    for (int ds = 0; ds < 4; ds++) {
        int c = (ds * 16 + lr) * 4 + h;
        int n = n0 + lg * 4;
        unsigned long long pk =
            (unsigned long long)f2bf(oacc[ds][0]) |
            ((unsigned long long)f2bf(oacc[ds][1]) << 16) |
            ((unsigned long long)f2bf(oacc[ds][2]) << 32) |
            ((unsigned long long)f2bf(oacc[ds][3]) << 48);
        *(unsigned long long*)&op[(size_t)c * Nn + n] = pk;
    }
}

// ---------------- finish: sum partials, normalize, transpose -> attnT[n][c] bf16 ----------------
__global__ __launch_bounds__(256) void k_finish(const unsigned short* __restrict__ opart,
                                                const float* __restrict__ denp,
                                                unsigned short* __restrict__ attnT) {
    __shared__ float t[64][65];
    const int cb = blockIdx.y * 64, nb = blockIdx.x * 64;
    const int tid = threadIdx.x;
    #pragma unroll
    for (int e = 0; e < 16; e++) {
        int idx = e * 256 + tid;
        int c_l = idx >> 6, n_l = idx & 63;
        int c = cb + c_l, n = nb + n_l;
        float s = 0.f;
        #pragma unroll
        for (int y = 0; y < 4; y++)
            s += bf2f(opart[(size_t)y * (Dm*Nn) + (size_t)c * Nn + n]);
        size_t row = (size_t)(c & 3) * Nn + n;
        float d = denp[row*4] + denp[row*4+1] + denp[row*4+2] + denp[row*4+3];
        t[c_l][n_l] = s / d;
    }
    __syncthreads();
    #pragma unroll
    for (int e = 0; e < 16; e++) {
        int idx = e * 256 + tid;
        int n_l = idx >> 6, c_l = idx & 63;
        attnT[(size_t)(nb + n_l) * 256 + cb + c_l] = f2bf(t[c_l][n_l]);
    }
}

extern "C" void kernel_launch(void* const* d_in, const int* in_sizes, int n_in,
                              void* d_out, int out_size, void* d_ws, size_t ws_size,
                              hipStream_t stream) {
    const float* x      = (const float*)d_in[0];
    const float* source = (const float*)d_in[1];
    const void*  mask   = d_in[3];
    const float* Wq = (const float*)d_in[4];  const float* bq = (const float*)d_in[5];
    const float* Wk = (const float*)d_in[6];  const float* bk = (const float*)d_in[7];
    const float* Wv = (const float*)d_in[8];  const float* bv = (const float*)d_in[9];
    const float* Wm = (const float*)d_in[10]; const float* bm = (const float*)d_in[11];
    const float* W1 = (const float*)d_in[12]; const float* b1 = (const float*)d_in[13];
    const float* W2 = (const float*)d_in[14]; const float* b2 = (const float*)d_in[15];

    float* y    = (float*)d_out;                // [256,4096]
    float* wout = y + (size_t)Dm * Nn;          // [4096,4096]

    char* ws = (char*)d_ws;
    int*      flag  = (int*)(ws + OFF_FLAG);
    unsigned* skey  = (unsigned*)(ws + OFF_SMIN);
    unsigned* kmax  = (unsigned*)(ws + OFF_KMAX);
    float*    mtarr = (float*)(ws + OFF_MT);
    float*    denp  = (float*)(ws + OFF_DENP);
    unsigned short* wb    = (unsigned short*)(ws + OFF_WB);
    unsigned char*  bits  = (unsigned char*)(ws + OFF_BITS);
    unsigned short* qb    = (unsigned short*)(ws + OFF_QB);
    unsigned short* kb    = (unsigned short*)(ws + OFF_KB);
    unsigned short* vb    = (unsigned short*)(ws + OFF_VB);
    unsigned short* hcat  = (unsigned short*)(ws + OFF_HCAT);
    unsigned short* attnT = (unsigned short*)(ws + OFF_ATTNT);
    unsigned short* xt    = (unsigned short*)(ws + OFF_XT);
    unsigned short* st    = (unsigned short*)(ws + OFF_ST);
    unsigned short* opart = (unsigned short*)(ws + OFF_OPART);
    unsigned short* h1t   = (unsigned short*)(ws + OFF_H1T);

    k_prep<<<dim3(128, 4, 2), 256, 0, stream>>>(x, source, xt, st, hcat,
                                                (const unsigned char*)mask, flag, kmax, skey);
    k_maskbits<<<8192, 256, 0, stream>>>(mask, flag, bits);
    k_wcast<<<2560, 256, 0, stream>>>(Wq, Wk, Wv, Wm, W1, W2, wb);

    k_qkv<<<dim3(64, 4, 3), 256, 0, stream>>>(wb, bq, bk, bv, xt, st, qb, kb, vb);

    k_knorm<<<dim3(16, 4), 256, 0, stream>>>(kb, kmax);
    k_qnorm<<<64, 256, 0, stream>>>(qb, kmax, mtarr);

    k_min<<<dim3(32, 16), 512, 0, stream>>>(qb, kb, skey);

    k_wout<<<dim3(32, 16), 512, 0, stream>>>(qb, kb, (const unsigned long long*)bits, skey, wout);

    k_pv<<<dim3(32, 16), 512, 0, stream>>>(qb, kb, vb, (const unsigned long long*)bits,
                                           skey, mtarr, denp, opart);
    k_finish<<<dim3(64, 4), 256, 0, stream>>>(opart, denp, attnT);

    k_mgemm<256><<<dim3(64, 4), 256, 0, stream>>>(wb + WOFF_M, bm, attnT, hcat, 3);
    k_mgemm<512><<<dim3(64, 8), 256, 0, stream>>>(wb + WOFF_1, b1, hcat, h1t, 4);
    k_mgemm<512><<<dim3(64, 4), 256, 0, stream>>>(wb + WOFF_2, b2, h1t, y, 0);
}